// Round 3
// baseline (396.698 us; speedup 1.0000x reference)
//
#include <hip/hip_runtime.h>
#include <hip/hip_bf16.h>

typedef __bf16 bf16;
typedef __bf16 bf16x8 __attribute__((ext_vector_type(8)));
typedef __bf16 bf16x4v __attribute__((ext_vector_type(4)));
typedef float f32x4 __attribute__((ext_vector_type(4)));

#define D_MODEL 512
#define T_SEQ   4096
#define NH      8
#define DH      64
#define M_ROWS  8192   // B*T
#define QK_SCALE 0.18033688011112042f   // 0.125 * log2(e), folded into Q

// ---------------- kernel 0: dtype detector ----------------------------------
__global__ __launch_bounds__(64) void detect_dtype(const unsigned short* __restrict__ xr,
                                                   int* __restrict__ flag)
{
  int lane = threadIdx.x;
  int cnt = 0;
  for (int i = lane; i < 4096; i += 64) {
    unsigned short u = xr[i];
    int e = (u >> 7) & 0xFF;
    bool insane = (e >= 133) || (e > 0 && e <= 96) || (e == 0 && (u & 0x7F) != 0);
    cnt += insane ? 1 : 0;
  }
#pragma unroll
  for (int off = 32; off >= 1; off >>= 1) cnt += __shfl_xor(cnt, off);
  if (lane == 0) *flag = (cnt > 400) ? 1 : 0;   // 1 = inputs are fp32
}

// ---------------- kernel 0b: convert x to bf16 -------------------------------
__global__ __launch_bounds__(256) void convert_x(const void* __restrict__ xr,
                                                 const int* __restrict__ flag,
                                                 bf16* __restrict__ xb, int n)
{
  int i = (blockIdx.x * blockDim.x + threadIdx.x) * 4;
  if (i >= n) return;
  if (*flag) {
    float4 v = *(const float4*)((const float*)xr + i);
    __align__(8) bf16 o[4] = {(bf16)v.x, (bf16)v.y, (bf16)v.z, (bf16)v.w};
    *(uint2*)(xb + i) = *(uint2*)o;
  } else {
    *(uint2*)(xb + i) = *(const uint2*)((const bf16*)xr + i);
  }
}

// ---------------- kernel 0c: biases -> fp32, mask -> float shift -------------
__global__ __launch_bounds__(1024) void prep_aux(
    const void* b0, const void* b1, const void* b2, const void* b3,
    const int* __restrict__ mask,
    const int* __restrict__ flag, float* __restrict__ bf, float* __restrict__ mf)
{
  const void* ps[4] = {b0, b1, b2, b3};
  int fl = *flag;
  for (int t = threadIdx.x; t < 4 * D_MODEL; t += 1024) {
    int w = t >> 9, o = t & 511;
    bf[t] = fl ? ((const float*)ps[w])[o] : (float)((const bf16*)ps[w])[o];
  }
  for (int j = threadIdx.x; j < M_ROWS; j += 1024)
    mf[j] = mask[j] ? -16.0f : -1e30f;     // fixed-shift (exp2 domain) + mask
}

// ---------------- kernel 1: per-output-channel weight quant-dequant ----------
__global__ __launch_bounds__(256) void qdq_weights(
    const void* __restrict__ Wq, const void* __restrict__ Wk,
    const void* __restrict__ Wv, const void* __restrict__ Wo,
    const int* __restrict__ flag, bf16* __restrict__ out)
{
  int wave = threadIdx.x >> 6, lane = threadIdx.x & 63;
  int gid = blockIdx.x * 4 + wave;
  int w = gid >> 9, row = gid & 511;
  const void* W = (w == 0) ? Wq : (w == 1) ? Wk : (w == 2) ? Wv : Wo;
  int fl = *flag;
  float v[8]; float amax = 0.f;
#pragma unroll
  for (int i = 0; i < 8; i++) {
    int idx = row * D_MODEL + lane + 64 * i;
    v[i] = fl ? ((const float*)W)[idx] : (float)((const bf16*)W)[idx];
    amax = fmaxf(amax, fabsf(v[i]));
  }
#pragma unroll
  for (int off = 32; off >= 1; off >>= 1) amax = fmaxf(amax, __shfl_xor(amax, off));
  float s = fmaxf(amax / 127.0f, 1e-8f);
  bf16* dst = out + (size_t)gid * D_MODEL;
#pragma unroll
  for (int i = 0; i < 8; i++) {
    float q = rintf(v[i] / s);
    q = fminf(fmaxf(q, -127.f), 127.f);
    dst[lane + 64*i] = (bf16)(q * s);
  }
}

// ---------------- kernel 2a: fused QKV GEMM ----------------------------------
#define LDS_STRIDE 40
__global__ __launch_bounds__(256) void gemm_qkv(
    const bf16* __restrict__ A, const bf16* __restrict__ W,
    const float* __restrict__ bias,
    bf16* __restrict__ Qm, bf16* __restrict__ Km, bf16* __restrict__ VT)
{
  __shared__ __align__(16) bf16 As[128 * LDS_STRIDE];
  __shared__ __align__(16) bf16 Bs[128 * LDS_STRIDE];

  const int tid = threadIdx.x;
  const int wave = tid >> 6, lane = tid & 63;
  const int lr = lane & 15, quad = lane >> 4;
  const int wm = (wave >> 1) * 64, wn = (wave & 1) * 64;
  const int m0 = blockIdx.x * 128, n0 = blockIdx.y * 128;
  const int sec = blockIdx.y >> 2;   // 0=Q 1=K 2=V

  f32x4 acc[4][4];
#pragma unroll
  for (int i = 0; i < 4; i++)
#pragma unroll
    for (int j = 0; j < 4; j++) acc[i][j] = f32x4{0.f, 0.f, 0.f, 0.f};

  const int srow = tid >> 2;
  const int sseg = (tid & 3) * 8;

  for (int k0 = 0; k0 < D_MODEL; k0 += 32) {
#pragma unroll
    for (int i = 0; i < 2; i++) {
      int r = srow + i * 64;
      *(uint4*)&As[r * LDS_STRIDE + sseg] = *(const uint4*)(A + (size_t)(m0 + r) * D_MODEL + k0 + sseg);
      *(uint4*)&Bs[r * LDS_STRIDE + sseg] = *(const uint4*)(W + (size_t)(n0 + r) * D_MODEL + k0 + sseg);
    }
    __syncthreads();
    bf16x8 af[4], bfr[4];
#pragma unroll
    for (int mt = 0; mt < 4; mt++) af[mt]  = *(bf16x8*)&As[(wm + mt*16 + lr) * LDS_STRIDE + quad*8];
#pragma unroll
    for (int nt = 0; nt < 4; nt++) bfr[nt] = *(bf16x8*)&Bs[(wn + nt*16 + lr) * LDS_STRIDE + quad*8];
#pragma unroll
    for (int mt = 0; mt < 4; mt++)
#pragma unroll
      for (int nt = 0; nt < 4; nt++)
        acc[mt][nt] = __builtin_amdgcn_mfma_f32_16x16x32_bf16(af[mt], bfr[nt], acc[mt][nt], 0, 0, 0);
    __syncthreads();
  }

  const float scale = (sec == 0) ? QK_SCALE : 1.0f;
#pragma unroll
  for (int mt = 0; mt < 4; mt++) {
    int grow = m0 + wm + mt * 16 + quad * 4;
#pragma unroll
    for (int nt = 0; nt < 4; nt++) {
      int gcol = n0 + wn + nt * 16 + lr;
      float b = bias[gcol];
      if (sec == 2) {               // VT[ch][token], packed x4
        bf16x4v pk;
#pragma unroll
        for (int r = 0; r < 4; r++) pk[r] = (bf16)(acc[mt][nt][r] + b);
        *(bf16x4v*)(VT + (size_t)(gcol - 1024) * M_ROWS + grow) = pk;
      } else {
        bf16* dst = (sec == 0) ? Qm : Km;
        int c = gcol & 511;
#pragma unroll
        for (int r = 0; r < 4; r++)
          dst[(size_t)(grow + r) * D_MODEL + c] = (bf16)((acc[mt][nt][r] + b) * scale);
      }
    }
  }
}

// ---------------- kernel 2b: O-proj GEMM, 64x128, fp32 out + absmax ----------
__global__ __launch_bounds__(256) void gemm_o(
    const bf16* __restrict__ A, const bf16* __restrict__ W,
    const float* __restrict__ bias,
    float* __restrict__ Cf, unsigned int* __restrict__ amaxp)
{
  __shared__ __align__(16) bf16 As[64 * LDS_STRIDE];
  __shared__ __align__(16) bf16 Bs[128 * LDS_STRIDE];
  __shared__ float wred[4];

  const int tid = threadIdx.x;
  const int wave = tid >> 6, lane = tid & 63;
  const int lr = lane & 15, quad = lane >> 4;
  const int wm = (wave >> 1) * 32, wn = (wave & 1) * 64;
  const int m0 = blockIdx.x * 64, n0 = blockIdx.y * 128;

  f32x4 acc[2][4];
#pragma unroll
  for (int i = 0; i < 2; i++)
#pragma unroll
    for (int j = 0; j < 4; j++) acc[i][j] = f32x4{0.f, 0.f, 0.f, 0.f};

  const int srow = tid >> 2;
  const int sseg = (tid & 3) * 8;

  for (int k0 = 0; k0 < D_MODEL; k0 += 32) {
    *(uint4*)&As[srow * LDS_STRIDE + sseg] = *(const uint4*)(A + (size_t)(m0 + srow) * D_MODEL + k0 + sseg);
#pragma unroll
    for (int i = 0; i < 2; i++) {
      int r = srow + i * 64;
      *(uint4*)&Bs[r * LDS_STRIDE + sseg] = *(const uint4*)(W + (size_t)(n0 + r) * D_MODEL + k0 + sseg);
    }
    __syncthreads();
    bf16x8 af[2], bfr[4];
#pragma unroll
    for (int mt = 0; mt < 2; mt++) af[mt]  = *(bf16x8*)&As[(wm + mt*16 + lr) * LDS_STRIDE + quad*8];
#pragma unroll
    for (int nt = 0; nt < 4; nt++) bfr[nt] = *(bf16x8*)&Bs[(wn + nt*16 + lr) * LDS_STRIDE + quad*8];
#pragma unroll
    for (int mt = 0; mt < 2; mt++)
#pragma unroll
      for (int nt = 0; nt < 4; nt++)
        acc[mt][nt] = __builtin_amdgcn_mfma_f32_16x16x32_bf16(af[mt], bfr[nt], acc[mt][nt], 0, 0, 0);
    __syncthreads();
  }

  float lmax = 0.f;
#pragma unroll
  for (int mt = 0; mt < 2; mt++) {
    int grow = m0 + wm + mt * 16 + quad * 4;
#pragma unroll
    for (int nt = 0; nt < 4; nt++) {
      int gcol = n0 + wn + nt * 16 + lr;
      float b = bias[gcol];
#pragma unroll
      for (int r = 0; r < 4; r++) {
        float v = acc[mt][nt][r] + b;
        Cf[(size_t)(grow + r) * D_MODEL + gcol] = v;
        lmax = fmaxf(lmax, fabsf(v));
      }
    }
  }
#pragma unroll
  for (int off = 32; off >= 1; off >>= 1) lmax = fmaxf(lmax, __shfl_xor(lmax, off));
  if (lane == 0) wred[wave] = lmax;
  __syncthreads();
  if (tid == 0) {
    float m = fmaxf(fmaxf(wred[0], wred[1]), fmaxf(wred[2], wred[3]));
    atomicMax(amaxp, __float_as_uint(m));
  }
}

// ---------------- kernel 3: split-K flash attention, high-TLP ----------------
// 2048 blocks x 128 thr (2 waves). Block owns 32 q-rows (QT=2) of one (b,h);
// wave w processes keys [2048w, 2048w+2048) = 32 chunks, 1-chunk prefetch.
// QT=2 keeps per-wave VGPR ~112 (R1 measured) -> 4 waves/SIMD resident
// (16 waves/CU): 4 independent wave streams cover each other's L2-latency
// stall windows (R2 at QT=4 had VGPR=172 -> only 2 waves/SIMD).
// L2 traffic 2x R2 (2.1 GB) but R1 showed bandwidth is not binding (8 TB/s
// agg vs 34.5 ceiling); latency-hiding capacity is. Main loop barrier-free;
// fixed exp2 shift (-16) => cross-wave (O,l) combine is plain addition.
// s_setprio(1) around MFMA clusters (T5: +4-7% on independent-wave attn).
#define PB_STRIDE 72
__global__ __launch_bounds__(128, 1) void attn(
    const bf16* __restrict__ Q, const bf16* __restrict__ K, const bf16* __restrict__ VT,
    const float* __restrict__ maskf, bf16* __restrict__ ctx)
{
  __shared__ __align__(16) bf16 Pb[2][32 * PB_STRIDE];   // 9216 B

  const int lane = threadIdx.x & 63;
  const int wave = threadIdx.x >> 6;        // key-half selector
  const int lr = lane & 15, quad = lane >> 4;
  // XCD swizzle: linear%8 = XCD -> give each XCD 2 bh values
  const int i = blockIdx.x;
  const int bh = (i & 7) * 2 + ((i >> 3) & 1);
  const int qb = i >> 4;                    // 0..127
  const int b = bh >> 3, h = bh & 7;
  const int q0 = qb * 32;

  const int kb0  = wave * 2048;
  const int kend = kb0 + 2048;
  bf16* Pw = Pb[wave];

  // Q as B-frags: qf[qt][kh], B[k=dh][n=q=lr]
  bf16x8 qf[2][2];
#pragma unroll
  for (int qt = 0; qt < 2; qt++) {
    const bf16* rq = Q + (size_t)(b * T_SEQ + q0 + qt*16 + lr) * D_MODEL + h * DH;
    qf[qt][0] = *(const bf16x8*)(rq + quad * 8);
    qf[qt][1] = *(const bf16x8*)(rq + 32 + quad * 8);
  }

  f32x4 O[2][4];   // O[qt][nt]: C-layout row=quad*4+r (q), col=lr (dh)
#pragma unroll
  for (int a = 0; a < 2; a++)
#pragma unroll
    for (int c = 0; c < 4; c++) O[a][c] = f32x4{0.f, 0.f, 0.f, 0.f};
  float lacc[2] = {0.f, 0.f};

  const bf16* Kb = K  + (size_t)(b * T_SEQ) * D_MODEL + h * DH;   // K[token][512]
  const bf16* Vb = VT + (size_t)(h * DH) * M_ROWS + b * T_SEQ;    // VT[dh][8192]
  const float* mb = maskf + b * T_SEQ;

  // A-frag K: kr[kt][kh] = K[kb+kt*16+lr][dh = kh*32+quad*8 ..+8]
  // B-frag V: vr[nt][ks] = V[key = ks*32+quad*8 ..+8][dh = nt*16+lr]
  bf16x8 kr[4][2], vr[4][2];
  f32x4 mk[4];
#pragma unroll
  for (int kt = 0; kt < 4; kt++) {
    const bf16* rk = Kb + (size_t)(kb0 + kt*16 + lr) * D_MODEL;
    kr[kt][0] = *(const bf16x8*)(rk + quad*8);
    kr[kt][1] = *(const bf16x8*)(rk + 32 + quad*8);
    mk[kt] = *(const f32x4*)(mb + kb0 + kt*16 + quad*4);
  }
#pragma unroll
  for (int nt = 0; nt < 4; nt++) {
    const bf16* rv = Vb + (size_t)(nt*16 + lr) * M_ROWS + kb0;
    vr[nt][0] = *(const bf16x8*)(rv + quad*8);
    vr[nt][1] = *(const bf16x8*)(rv + 32 + quad*8);
  }

  for (int kb = kb0; kb < kend; kb += 64) {
    const bool nxt = (kb + 64) < kend;

    // S^T = K.Q^T per (qt,kt); mask+shift as C-init; exp2 -> Pw
#pragma unroll
    for (int qt = 0; qt < 2; qt++) {
      f32x4 z[4];
      __builtin_amdgcn_s_setprio(1);
#pragma unroll
      for (int kt = 0; kt < 4; kt++) {
        f32x4 t = mk[kt];
        t = __builtin_amdgcn_mfma_f32_16x16x32_bf16(kr[kt][0], qf[qt][0], t, 0, 0, 0);
        t = __builtin_amdgcn_mfma_f32_16x16x32_bf16(kr[kt][1], qf[qt][1], t, 0, 0, 0);
        z[kt] = t;
      }
      __builtin_amdgcn_s_setprio(0);
      float la = lacc[qt];
#pragma unroll
      for (int kt = 0; kt < 4; kt++) {
        bf16x4v pk;
#pragma unroll
        for (int r = 0; r < 4; r++) {
          float p = __builtin_amdgcn_exp2f(z[kt][r]);
          la += p;
          pk[r] = (bf16)p;
        }
        *(bf16x4v*)&Pw[(qt*16 + lr) * PB_STRIDE + kt*16 + quad*4] = pk;
      }
      lacc[qt] = la;
    }

    if (nxt) {  // kr & mk dead -> prefetch next chunk's K + mask
#pragma unroll
      for (int kt = 0; kt < 4; kt++) {
        const bf16* rk = Kb + (size_t)(kb + 64 + kt*16 + lr) * D_MODEL;
        kr[kt][0] = *(const bf16x8*)(rk + quad*8);
        kr[kt][1] = *(const bf16x8*)(rk + 32 + quad*8);
        mk[kt] = *(const f32x4*)(mb + kb + 64 + kt*16 + quad*4);
      }
    }

    // P back as A-frags (same-wave LDS, ordered)
    bf16x8 pf[2][2];
#pragma unroll
    for (int qt = 0; qt < 2; qt++) {
      pf[qt][0] = *(bf16x8*)&Pw[(qt*16 + lr) * PB_STRIDE + quad*8];
      pf[qt][1] = *(bf16x8*)&Pw[(qt*16 + lr) * PB_STRIDE + 32 + quad*8];
    }

    // PV accumulate
    __builtin_amdgcn_s_setprio(1);
#pragma unroll
    for (int nt = 0; nt < 4; nt++)
#pragma unroll
      for (int qt = 0; qt < 2; qt++) {
        O[qt][nt] = __builtin_amdgcn_mfma_f32_16x16x32_bf16(pf[qt][0], vr[nt][0], O[qt][nt], 0, 0, 0);
        O[qt][nt] = __builtin_amdgcn_mfma_f32_16x16x32_bf16(pf[qt][1], vr[nt][1], O[qt][nt], 0, 0, 0);
      }
    __builtin_amdgcn_s_setprio(0);

    if (nxt) {  // vr dead -> prefetch next chunk's V
#pragma unroll
      for (int nt = 0; nt < 4; nt++) {
        const bf16* rv = Vb + (size_t)(nt*16 + lr) * M_ROWS + kb + 64;
        vr[nt][0] = *(const bf16x8*)(rv + quad*8);
        vr[nt][1] = *(const bf16x8*)(rv + 32 + quad*8);
      }
    }
  }

  // ---- cross-wave combine: O += O_other, l += l_other (fixed shift => add) --
  __syncthreads();                       // both waves done with their Pb
  float* Osh = (float*)&Pb[0][0];        // 8192 B (overlays dead Pb)
  float* Lsh = Osh + 2048;               // 512 B
  if (wave == 1) {
#pragma unroll
    for (int qt = 0; qt < 2; qt++) {
#pragma unroll
      for (int nt = 0; nt < 4; nt++)
        *(f32x4*)&Osh[((qt*4 + nt) * 64 + lane) * 4] = O[qt][nt];
      Lsh[qt * 64 + lane] = lacc[qt];
    }
  }
  __syncthreads();
  if (wave == 0) {
#pragma unroll
    for (int qt = 0; qt < 2; qt++) {
#pragma unroll
      for (int nt = 0; nt < 4; nt++) {
        f32x4 o2 = *(const f32x4*)&Osh[((qt*4 + nt) * 64 + lane) * 4];
        O[qt][nt] += o2;
      }
      lacc[qt] += Lsh[qt * 64 + lane];
    }

    // epilogue: normalize + store
#pragma unroll
    for (int qt = 0; qt < 2; qt++) {
      float ls = lacc[qt];
      ls += __shfl_xor(ls, 16);
      ls += __shfl_xor(ls, 32);
      float linv = 1.0f / ls;
      float lO[4];
#pragma unroll
      for (int r = 0; r < 4; r++) lO[r] = __shfl(linv, quad*4 + r);
#pragma unroll
      for (int nt = 0; nt < 4; nt++)
#pragma unroll
        for (int r = 0; r < 4; r++) {
          size_t row = (size_t)(b * T_SEQ + q0 + qt*16 + quad*4 + r);
          ctx[row * D_MODEL + h * DH + nt*16 + lr] = (bf16)(O[qt][nt][r] * lO[r]);
        }
    }
  }
}

// ---------------- kernel 4: per-tensor activation quant-dequant --------------
__global__ __launch_bounds__(256) void act_qdq(
    const float* __restrict__ pre, const unsigned int* __restrict__ amaxp,
    const int* __restrict__ flag, void* __restrict__ outv, int n)
{
  int i = (blockIdx.x * blockDim.x + threadIdx.x) * 4;
  if (i >= n) return;
  float s = fmaxf(__uint_as_float(*amaxp) / 127.0f, 1e-8f);
  float4 v = *(const float4*)(pre + i);
  float o[4] = {v.x, v.y, v.z, v.w};
#pragma unroll
  for (int r = 0; r < 4; r++) {
    float q = rintf(o[r] / s);
    q = fminf(fmaxf(q, -127.f), 127.f);
    o[r] = q * s;
  }
  if (*flag) {
    *(float4*)((float*)outv + i) = make_float4(o[0], o[1], o[2], o[3]);
  } else {
    __align__(8) bf16 ob[4] = {(bf16)o[0], (bf16)o[1], (bf16)o[2], (bf16)o[3]};
    *(uint2*)((bf16*)outv + i) = *(uint2*)ob;
  }
}

// ---------------- launch -----------------------------------------------------
extern "C" void kernel_launch(void* const* d_in, const int* in_sizes, int n_in,
                              void* d_out, int out_size, void* d_ws, size_t ws_size,
                              hipStream_t stream) {
  const void* x    = d_in[0];
  const int*  mask = (const int*)d_in[1];
  const void* Wq = d_in[2]; const void* bq = d_in[3];
  const void* Wk = d_in[4]; const void* bk = d_in[5];
  const void* Wv = d_in[6]; const void* bv = d_in[7];
  const void* Wo = d_in[8]; const void* bo = d_in[9];

  char* ws = (char*)d_ws;
  int*  flag  = (int*)(ws + 0);
  unsigned int* amax = (unsigned int*)(ws + 64);
  float* biasf = (float*)(ws + 1024);                 // 8 KB
  float* maskf = (float*)(ws + 16384);                // 32 KB
  bf16* Wt  = (bf16*)(ws + 65536);                    // 2 MB
  bf16* xb  = (bf16*)(ws + 4194304);                  // 8 MB
  bf16* Qm  = (bf16*)(ws + 12582912);                 // 8 MB (pre-scaled)
  bf16* Km  = (bf16*)(ws + 20971520);                 // 8 MB
  bf16* VT  = (bf16*)(ws + 29360128);                 // 8 MB: VT[ch][token]
  bf16* Cm  = (bf16*)(ws + 4194304);                  // overlays xb
  float* pre = (float*)(ws + 12582912);               // overlays Qm+Km

  hipMemsetAsync(amax, 0, 4, stream);
  detect_dtype<<<1, 64, 0, stream>>>((const unsigned short*)x, flag);
  convert_x<<<4096, 256, 0, stream>>>(x, flag, xb, M_ROWS * D_MODEL);
  prep_aux<<<1, 1024, 0, stream>>>(bq, bk, bv, bo, mask, flag, biasf, maskf);
  qdq_weights<<<512, 256, 0, stream>>>(Wq, Wk, Wv, Wo, flag, Wt);
  gemm_qkv<<<dim3(64, 12), 256, 0, stream>>>(xb, Wt, biasf, Qm, Km, VT);
  attn<<<2048, 128, 0, stream>>>(Qm, Km, VT, maskf, Cm);
  gemm_o<<<dim3(128, 4), 256, 0, stream>>>(Cm, Wt + 3*262144, biasf + 1536, pre, amax);
  act_qdq<<<4096, 256, 0, stream>>>(pre, amax, flag, d_out, M_ROWS * D_MODEL);
}

// Round 4
// 262.925 us; speedup vs baseline: 1.5088x; 1.5088x over previous
//
#include <hip/hip_runtime.h>
#include <hip/hip_bf16.h>

typedef __bf16 bf16;
typedef __bf16 bf16x8 __attribute__((ext_vector_type(8)));
typedef __bf16 bf16x4v __attribute__((ext_vector_type(4)));
typedef float f32x4 __attribute__((ext_vector_type(4)));

#define D_MODEL 512
#define T_SEQ   4096
#define NH      8
#define DH      64
#define M_ROWS  8192   // B*T
#define VROW    8224   // 8192 + 32 pad tokens: V row stride 16448 B (non-pow2)
#define QK_SCALE 0.18033688011112042f   // 0.125 * log2(e), folded into Q

// ---------------- kernel 0: dtype detector ----------------------------------
__global__ __launch_bounds__(64) void detect_dtype(const unsigned short* __restrict__ xr,
                                                   int* __restrict__ flag)
{
  int lane = threadIdx.x;
  int cnt = 0;
  for (int i = lane; i < 4096; i += 64) {
    unsigned short u = xr[i];
    int e = (u >> 7) & 0xFF;
    bool insane = (e >= 133) || (e > 0 && e <= 96) || (e == 0 && (u & 0x7F) != 0);
    cnt += insane ? 1 : 0;
  }
#pragma unroll
  for (int off = 32; off >= 1; off >>= 1) cnt += __shfl_xor(cnt, off);
  if (lane == 0) *flag = (cnt > 400) ? 1 : 0;   // 1 = inputs are fp32
}

// ---------------- kernel 0b: convert x to bf16 -------------------------------
__global__ __launch_bounds__(256) void convert_x(const void* __restrict__ xr,
                                                 const int* __restrict__ flag,
                                                 bf16* __restrict__ xb, int n)
{
  int i = (blockIdx.x * blockDim.x + threadIdx.x) * 4;
  if (i >= n) return;
  if (*flag) {
    float4 v = *(const float4*)((const float*)xr + i);
    __align__(8) bf16 o[4] = {(bf16)v.x, (bf16)v.y, (bf16)v.z, (bf16)v.w};
    *(uint2*)(xb + i) = *(uint2*)o;
  } else {
    *(uint2*)(xb + i) = *(const uint2*)((const bf16*)xr + i);
  }
}

// ---------------- kernel 0c: biases -> fp32, mask -> float shift -------------
__global__ __launch_bounds__(1024) void prep_aux(
    const void* b0, const void* b1, const void* b2, const void* b3,
    const int* __restrict__ mask,
    const int* __restrict__ flag, float* __restrict__ bf, float* __restrict__ mf)
{
  const void* ps[4] = {b0, b1, b2, b3};
  int fl = *flag;
  for (int t = threadIdx.x; t < 4 * D_MODEL; t += 1024) {
    int w = t >> 9, o = t & 511;
    bf[t] = fl ? ((const float*)ps[w])[o] : (float)((const bf16*)ps[w])[o];
  }
  for (int j = threadIdx.x; j < M_ROWS; j += 1024)
    mf[j] = mask[j] ? -16.0f : -1e30f;     // fixed-shift (exp2 domain) + mask
}

// ---------------- kernel 1: per-output-channel weight quant-dequant ----------
__global__ __launch_bounds__(256) void qdq_weights(
    const void* __restrict__ Wq, const void* __restrict__ Wk,
    const void* __restrict__ Wv, const void* __restrict__ Wo,
    const int* __restrict__ flag, bf16* __restrict__ out)
{
  int wave = threadIdx.x >> 6, lane = threadIdx.x & 63;
  int gid = blockIdx.x * 4 + wave;
  int w = gid >> 9, row = gid & 511;
  const void* W = (w == 0) ? Wq : (w == 1) ? Wk : (w == 2) ? Wv : Wo;
  int fl = *flag;
  float v[8]; float amax = 0.f;
#pragma unroll
  for (int i = 0; i < 8; i++) {
    int idx = row * D_MODEL + lane + 64 * i;
    v[i] = fl ? ((const float*)W)[idx] : (float)((const bf16*)W)[idx];
    amax = fmaxf(amax, fabsf(v[i]));
  }
#pragma unroll
  for (int off = 32; off >= 1; off >>= 1) amax = fmaxf(amax, __shfl_xor(amax, off));
  float s = fmaxf(amax / 127.0f, 1e-8f);
  bf16* dst = out + (size_t)gid * D_MODEL;
#pragma unroll
  for (int i = 0; i < 8; i++) {
    float q = rintf(v[i] / s);
    q = fminf(fmaxf(q, -127.f), 127.f);
    dst[lane + 64*i] = (bf16)(q * s);
  }
}

// ---------------- kernel 2a: fused QKV GEMM ----------------------------------
// Q/K written HEAD-MAJOR: Qh/Kh[(b*8+h)][t 0..4095][64] (contiguous per head)
// V written to VTP[ch 0..511][VROW tokens] (row stride 16448 B, non-pow2)
#define LDS_STRIDE 40
__global__ __launch_bounds__(256) void gemm_qkv(
    const bf16* __restrict__ A, const bf16* __restrict__ W,
    const float* __restrict__ bias,
    bf16* __restrict__ Qh, bf16* __restrict__ Kh, bf16* __restrict__ VTP)
{
  __shared__ __align__(16) bf16 As[128 * LDS_STRIDE];
  __shared__ __align__(16) bf16 Bs[128 * LDS_STRIDE];

  const int tid = threadIdx.x;
  const int wave = tid >> 6, lane = tid & 63;
  const int lr = lane & 15, quad = lane >> 4;
  const int wm = (wave >> 1) * 64, wn = (wave & 1) * 64;
  const int m0 = blockIdx.x * 128, n0 = blockIdx.y * 128;
  const int sec = blockIdx.y >> 2;   // 0=Q 1=K 2=V

  f32x4 acc[4][4];
#pragma unroll
  for (int i = 0; i < 4; i++)
#pragma unroll
    for (int j = 0; j < 4; j++) acc[i][j] = f32x4{0.f, 0.f, 0.f, 0.f};

  const int srow = tid >> 2;
  const int sseg = (tid & 3) * 8;

  for (int k0 = 0; k0 < D_MODEL; k0 += 32) {
#pragma unroll
    for (int i = 0; i < 2; i++) {
      int r = srow + i * 64;
      *(uint4*)&As[r * LDS_STRIDE + sseg] = *(const uint4*)(A + (size_t)(m0 + r) * D_MODEL + k0 + sseg);
      *(uint4*)&Bs[r * LDS_STRIDE + sseg] = *(const uint4*)(W + (size_t)(n0 + r) * D_MODEL + k0 + sseg);
    }
    __syncthreads();
    bf16x8 af[4], bfr[4];
#pragma unroll
    for (int mt = 0; mt < 4; mt++) af[mt]  = *(bf16x8*)&As[(wm + mt*16 + lr) * LDS_STRIDE + quad*8];
#pragma unroll
    for (int nt = 0; nt < 4; nt++) bfr[nt] = *(bf16x8*)&Bs[(wn + nt*16 + lr) * LDS_STRIDE + quad*8];
#pragma unroll
    for (int mt = 0; mt < 4; mt++)
#pragma unroll
      for (int nt = 0; nt < 4; nt++)
        acc[mt][nt] = __builtin_amdgcn_mfma_f32_16x16x32_bf16(af[mt], bfr[nt], acc[mt][nt], 0, 0, 0);
    __syncthreads();
  }

  const float scale = (sec == 0) ? QK_SCALE : 1.0f;
#pragma unroll
  for (int mt = 0; mt < 4; mt++) {
    int grow = m0 + wm + mt * 16 + quad * 4;
#pragma unroll
    for (int nt = 0; nt < 4; nt++) {
      int gcol = n0 + wn + nt * 16 + lr;
      float b = bias[gcol];
      if (sec == 2) {               // VTP[ch][token], packed x4, padded row
        bf16x4v pk;
#pragma unroll
        for (int r = 0; r < 4; r++) pk[r] = (bf16)(acc[mt][nt][r] + b);
        *(bf16x4v*)(VTP + (size_t)(gcol - 1024) * VROW + grow) = pk;
      } else {                      // head-major planes
        bf16* dst = (sec == 0) ? Qh : Kh;
        int c = gcol & 511;
        int hh = c >> 6, c64 = c & 63;
#pragma unroll
        for (int r = 0; r < 4; r++) {
          int row = grow + r;
          int bb = row >> 12, t = row & 4095;
          dst[((size_t)(bb * NH + hh) * T_SEQ + t) * DH + c64] =
              (bf16)((acc[mt][nt][r] + b) * scale);
        }
      }
    }
  }
}

// ---------------- kernel 2b: O-proj GEMM, 64x128, fp32 out + absmax ----------
__global__ __launch_bounds__(256) void gemm_o(
    const bf16* __restrict__ A, const bf16* __restrict__ W,
    const float* __restrict__ bias,
    float* __restrict__ Cf, unsigned int* __restrict__ amaxp)
{
  __shared__ __align__(16) bf16 As[64 * LDS_STRIDE];
  __shared__ __align__(16) bf16 Bs[128 * LDS_STRIDE];
  __shared__ float wred[4];

  const int tid = threadIdx.x;
  const int wave = tid >> 6, lane = tid & 63;
  const int lr = lane & 15, quad = lane >> 4;
  const int wm = (wave >> 1) * 32, wn = (wave & 1) * 64;
  const int m0 = blockIdx.x * 64, n0 = blockIdx.y * 128;

  f32x4 acc[2][4];
#pragma unroll
  for (int i = 0; i < 2; i++)
#pragma unroll
    for (int j = 0; j < 4; j++) acc[i][j] = f32x4{0.f, 0.f, 0.f, 0.f};

  const int srow = tid >> 2;
  const int sseg = (tid & 3) * 8;

  for (int k0 = 0; k0 < D_MODEL; k0 += 32) {
    *(uint4*)&As[srow * LDS_STRIDE + sseg] = *(const uint4*)(A + (size_t)(m0 + srow) * D_MODEL + k0 + sseg);
#pragma unroll
    for (int i = 0; i < 2; i++) {
      int r = srow + i * 64;
      *(uint4*)&Bs[r * LDS_STRIDE + sseg] = *(const uint4*)(W + (size_t)(n0 + r) * D_MODEL + k0 + sseg);
    }
    __syncthreads();
    bf16x8 af[2], bfr[4];
#pragma unroll
    for (int mt = 0; mt < 2; mt++) af[mt]  = *(bf16x8*)&As[(wm + mt*16 + lr) * LDS_STRIDE + quad*8];
#pragma unroll
    for (int nt = 0; nt < 4; nt++) bfr[nt] = *(bf16x8*)&Bs[(wn + nt*16 + lr) * LDS_STRIDE + quad*8];
#pragma unroll
    for (int mt = 0; mt < 2; mt++)
#pragma unroll
      for (int nt = 0; nt < 4; nt++)
        acc[mt][nt] = __builtin_amdgcn_mfma_f32_16x16x32_bf16(af[mt], bfr[nt], acc[mt][nt], 0, 0, 0);
    __syncthreads();
  }

  float lmax = 0.f;
#pragma unroll
  for (int mt = 0; mt < 2; mt++) {
    int grow = m0 + wm + mt * 16 + quad * 4;
#pragma unroll
    for (int nt = 0; nt < 4; nt++) {
      int gcol = n0 + wn + nt * 16 + lr;
      float b = bias[gcol];
#pragma unroll
      for (int r = 0; r < 4; r++) {
        float v = acc[mt][nt][r] + b;
        Cf[(size_t)(grow + r) * D_MODEL + gcol] = v;
        lmax = fmaxf(lmax, fabsf(v));
      }
    }
  }
#pragma unroll
  for (int off = 32; off >= 1; off >>= 1) lmax = fmaxf(lmax, __shfl_xor(lmax, off));
  if (lane == 0) wred[wave] = lmax;
  __syncthreads();
  if (tid == 0) {
    float m = fmaxf(fmaxf(wred[0], wred[1]), fmaxf(wred[2], wred[3]));
    atomicMax(amaxp, __float_as_uint(m));
  }
}

// ---------------- kernel 3: split-K flash attention (R2 structure) -----------
// 1024 blocks x 128 thr (2 waves). Block owns 64 q-rows of one (b,h);
// wave w processes keys [2048w, 2048w+2048). Fixed exp2 shift (-16) =>
// cross-wave (O,l) combine is plain addition via LDS. Main loop barrier-free.
// R4 change: K/Q head-major contiguous planes, V padded rows -> kills the
// pow2-stride (1KB/16KB) address bands that pinned agg load BW at ~7.5 TB/s
// across R0-R3 regardless of occupancy (L2 channel conflicts).
#define PB_STRIDE 72
__global__ __launch_bounds__(128, 1) void attn(
    const bf16* __restrict__ Q, const bf16* __restrict__ K, const bf16* __restrict__ VT,
    const float* __restrict__ maskf, bf16* __restrict__ ctx)
{
  __shared__ __align__(16) bf16 Pb[2][64 * PB_STRIDE];   // 18432 B

  const int lane = threadIdx.x & 63;
  const int wave = threadIdx.x >> 6;        // key-half selector
  const int lr = lane & 15, quad = lane >> 4;
  // XCD swizzle: linear%8 = XCD -> give each XCD 2 bh values
  const int i = blockIdx.x;
  const int bh = (i & 7) * 2 + ((i >> 3) & 1);
  const int qb = i >> 4;                    // 0..63
  const int b = bh >> 3, h = bh & 7;
  const int q0 = qb * 64;

  const int kb0  = wave * 2048;
  const int kend = kb0 + 2048;
  bf16* Pw = Pb[wave];

  const bf16* Qb = Q  + (size_t)bh * T_SEQ * DH;       // Qh[bh][t][64]
  const bf16* Kb = K  + (size_t)bh * T_SEQ * DH;       // Kh[bh][t][64]
  const bf16* Vb = VT + (size_t)(h * DH) * VROW + b * T_SEQ;  // VTP[ch][VROW]
  const float* mb = maskf + b * T_SEQ;

  // Q as B-frags: qf[qt][kh], B[k=dh][n=q=lr]
  bf16x8 qf[4][2];
#pragma unroll
  for (int qt = 0; qt < 4; qt++) {
    const bf16* rq = Qb + (size_t)(q0 + qt*16 + lr) * DH;
    qf[qt][0] = *(const bf16x8*)(rq + quad * 8);
    qf[qt][1] = *(const bf16x8*)(rq + 32 + quad * 8);
  }

  f32x4 O[4][4];   // O[qt][nt]: C-layout row=quad*4+r (q), col=lr (dh)
#pragma unroll
  for (int a = 0; a < 4; a++)
#pragma unroll
    for (int c = 0; c < 4; c++) O[a][c] = f32x4{0.f, 0.f, 0.f, 0.f};
  float lacc[4] = {0.f, 0.f, 0.f, 0.f};

  // A-frag K: kr[kt][kh] = K[kb+kt*16+lr][dh = kh*32+quad*8 ..+8]
  // B-frag V: vr[nt][ks] = V[key = ks*32+quad*8 ..+8][dh = nt*16+lr]
  bf16x8 kr[4][2], vr[4][2];
  f32x4 mk[4];
#pragma unroll
  for (int kt = 0; kt < 4; kt++) {
    const bf16* rk = Kb + (size_t)(kb0 + kt*16 + lr) * DH;
    kr[kt][0] = *(const bf16x8*)(rk + quad*8);
    kr[kt][1] = *(const bf16x8*)(rk + 32 + quad*8);
    mk[kt] = *(const f32x4*)(mb + kb0 + kt*16 + quad*4);
  }
#pragma unroll
  for (int nt = 0; nt < 4; nt++) {
    const bf16* rv = Vb + (size_t)(nt*16 + lr) * VROW + kb0;
    vr[nt][0] = *(const bf16x8*)(rv + quad*8);
    vr[nt][1] = *(const bf16x8*)(rv + 32 + quad*8);
  }

  for (int kb = kb0; kb < kend; kb += 64) {
    const bool nxt = (kb + 64) < kend;

    // S^T = K.Q^T per (qt,kt); mask+shift as C-init; exp2 -> Pw
#pragma unroll
    for (int qt = 0; qt < 4; qt++) {
      f32x4 z[4];
#pragma unroll
      for (int kt = 0; kt < 4; kt++) {
        f32x4 t = mk[kt];
        t = __builtin_amdgcn_mfma_f32_16x16x32_bf16(kr[kt][0], qf[qt][0], t, 0, 0, 0);
        t = __builtin_amdgcn_mfma_f32_16x16x32_bf16(kr[kt][1], qf[qt][1], t, 0, 0, 0);
        z[kt] = t;
      }
      float la = lacc[qt];
#pragma unroll
      for (int kt = 0; kt < 4; kt++) {
        bf16x4v pk;
#pragma unroll
        for (int r = 0; r < 4; r++) {
          float p = __builtin_amdgcn_exp2f(z[kt][r]);
          la += p;
          pk[r] = (bf16)p;
        }
        *(bf16x4v*)&Pw[(qt*16 + lr) * PB_STRIDE + kt*16 + quad*4] = pk;
      }
      lacc[qt] = la;
    }

    if (nxt) {  // kr & mk dead -> prefetch next chunk's K + mask
#pragma unroll
      for (int kt = 0; kt < 4; kt++) {
        const bf16* rk = Kb + (size_t)(kb + 64 + kt*16 + lr) * DH;
        kr[kt][0] = *(const bf16x8*)(rk + quad*8);
        kr[kt][1] = *(const bf16x8*)(rk + 32 + quad*8);
        mk[kt] = *(const f32x4*)(mb + kb + 64 + kt*16 + quad*4);
      }
    }

    // P back as A-frags (same-wave LDS, ordered)
    bf16x8 pf[4][2];
#pragma unroll
    for (int qt = 0; qt < 4; qt++) {
      pf[qt][0] = *(bf16x8*)&Pw[(qt*16 + lr) * PB_STRIDE + quad*8];
      pf[qt][1] = *(bf16x8*)&Pw[(qt*16 + lr) * PB_STRIDE + 32 + quad*8];
    }

    // PV accumulate
#pragma unroll
    for (int nt = 0; nt < 4; nt++)
#pragma unroll
      for (int qt = 0; qt < 4; qt++) {
        O[qt][nt] = __builtin_amdgcn_mfma_f32_16x16x32_bf16(pf[qt][0], vr[nt][0], O[qt][nt], 0, 0, 0);
        O[qt][nt] = __builtin_amdgcn_mfma_f32_16x16x32_bf16(pf[qt][1], vr[nt][1], O[qt][nt], 0, 0, 0);
      }

    if (nxt) {  // vr dead -> prefetch next chunk's V
#pragma unroll
      for (int nt = 0; nt < 4; nt++) {
        const bf16* rv = Vb + (size_t)(nt*16 + lr) * VROW + kb + 64;
        vr[nt][0] = *(const bf16x8*)(rv + quad*8);
        vr[nt][1] = *(const bf16x8*)(rv + 32 + quad*8);
      }
    }
  }

  // ---- cross-wave combine: O += O_other, l += l_other (fixed shift => add) --
  __syncthreads();                       // both waves done with their Pb
  float* Osh = (float*)&Pb[0][0];        // 16384 B (overlays dead Pb)
  float* Lsh = Osh + 4096;               // 1024 B
  if (wave == 1) {
#pragma unroll
    for (int qt = 0; qt < 4; qt++) {
#pragma unroll
      for (int nt = 0; nt < 4; nt++)
        *(f32x4*)&Osh[((qt*4 + nt) * 64 + lane) * 4] = O[qt][nt];
      Lsh[qt * 64 + lane] = lacc[qt];
    }
  }
  __syncthreads();
  if (wave == 0) {
#pragma unroll
    for (int qt = 0; qt < 4; qt++) {
#pragma unroll
      for (int nt = 0; nt < 4; nt++) {
        f32x4 o2 = *(const f32x4*)&Osh[((qt*4 + nt) * 64 + lane) * 4];
        O[qt][nt] += o2;
      }
      lacc[qt] += Lsh[qt * 64 + lane];
    }

    // epilogue: normalize + store
#pragma unroll
    for (int qt = 0; qt < 4; qt++) {
      float ls = lacc[qt];
      ls += __shfl_xor(ls, 16);
      ls += __shfl_xor(ls, 32);
      float linv = 1.0f / ls;
      float lO[4];
#pragma unroll
      for (int r = 0; r < 4; r++) lO[r] = __shfl(linv, quad*4 + r);
#pragma unroll
      for (int nt = 0; nt < 4; nt++)
#pragma unroll
        for (int r = 0; r < 4; r++) {
          size_t row = (size_t)(b * T_SEQ + q0 + qt*16 + quad*4 + r);
          ctx[row * D_MODEL + h * DH + nt*16 + lr] = (bf16)(O[qt][nt][r] * lO[r]);
        }
    }
  }
}

// ---------------- kernel 4: per-tensor activation quant-dequant --------------
__global__ __launch_bounds__(256) void act_qdq(
    const float* __restrict__ pre, const unsigned int* __restrict__ amaxp,
    const int* __restrict__ flag, void* __restrict__ outv, int n)
{
  int i = (blockIdx.x * blockDim.x + threadIdx.x) * 4;
  if (i >= n) return;
  float s = fmaxf(__uint_as_float(*amaxp) / 127.0f, 1e-8f);
  float4 v = *(const float4*)(pre + i);
  float o[4] = {v.x, v.y, v.z, v.w};
#pragma unroll
  for (int r = 0; r < 4; r++) {
    float q = rintf(o[r] / s);
    q = fminf(fmaxf(q, -127.f), 127.f);
    o[r] = q * s;
  }
  if (*flag) {
    *(float4*)((float*)outv + i) = make_float4(o[0], o[1], o[2], o[3]);
  } else {
    __align__(8) bf16 ob[4] = {(bf16)o[0], (bf16)o[1], (bf16)o[2], (bf16)o[3]};
    *(uint2*)((bf16*)outv + i) = *(uint2*)ob;
  }
}

// ---------------- launch -----------------------------------------------------
extern "C" void kernel_launch(void* const* d_in, const int* in_sizes, int n_in,
                              void* d_out, int out_size, void* d_ws, size_t ws_size,
                              hipStream_t stream) {
  const void* x    = d_in[0];
  const int*  mask = (const int*)d_in[1];
  const void* Wq = d_in[2]; const void* bq = d_in[3];
  const void* Wk = d_in[4]; const void* bk = d_in[5];
  const void* Wv = d_in[6]; const void* bv = d_in[7];
  const void* Wo = d_in[8]; const void* bo = d_in[9];

  char* ws = (char*)d_ws;
  int*  flag  = (int*)(ws + 0);
  unsigned int* amax = (unsigned int*)(ws + 64);
  float* biasf = (float*)(ws + 1024);                 // 8 KB
  float* maskf = (float*)(ws + 16384);                // 32 KB
  bf16* Wt  = (bf16*)(ws + 65536);                    // 2 MB
  bf16* xb  = (bf16*)(ws + 4194304);                  // 8 MB
  bf16* Qm  = (bf16*)(ws + 12582912);                 // 8 MB head-major planes
  bf16* Km  = (bf16*)(ws + 20971520);                 // 8 MB head-major planes
  bf16* VT  = (bf16*)(ws + 29360128);                 // 8.42 MB: VTP[ch][8224]
  bf16* Cm  = (bf16*)(ws + 4194304);                  // overlays xb
  float* pre = (float*)(ws + 12582912);               // overlays Qm+Km

  hipMemsetAsync(amax, 0, 4, stream);
  detect_dtype<<<1, 64, 0, stream>>>((const unsigned short*)x, flag);
  convert_x<<<4096, 256, 0, stream>>>(x, flag, xb, M_ROWS * D_MODEL);
  prep_aux<<<1, 1024, 0, stream>>>(bq, bk, bv, bo, mask, flag, biasf, maskf);
  qdq_weights<<<512, 256, 0, stream>>>(Wq, Wk, Wv, Wo, flag, Wt);
  gemm_qkv<<<dim3(64, 12), 256, 0, stream>>>(xb, Wt, biasf, Qm, Km, VT);
  attn<<<1024, 128, 0, stream>>>(Qm, Km, VT, maskf, Cm);
  gemm_o<<<dim3(128, 4), 256, 0, stream>>>(Cm, Wt + 3*262144, biasf + 1536, pre, amax);
  act_qdq<<<4096, 256, 0, stream>>>(pre, amax, flag, d_out, M_ROWS * D_MODEL);
}

// Round 5
// 261.808 us; speedup vs baseline: 1.5152x; 1.0043x over previous
//
#include <hip/hip_runtime.h>
#include <hip/hip_bf16.h>

typedef __bf16 bf16;
typedef __bf16 bf16x8 __attribute__((ext_vector_type(8)));
typedef __bf16 bf16x4v __attribute__((ext_vector_type(4)));
typedef float f32x4 __attribute__((ext_vector_type(4)));

#define D_MODEL 512
#define T_SEQ   4096
#define NH      8
#define DH      64
#define M_ROWS  8192   // B*T
#define VROW    8224   // 8192 + 32 pad tokens: V row stride 16448 B (non-pow2)
#define QK_SCALE 0.18033688011112042f   // 0.125 * log2(e), folded into Q

// ---------------- kernel 0: dtype detector ----------------------------------
__global__ __launch_bounds__(64) void detect_dtype(const unsigned short* __restrict__ xr,
                                                   int* __restrict__ flag)
{
  int lane = threadIdx.x;
  int cnt = 0;
  for (int i = lane; i < 4096; i += 64) {
    unsigned short u = xr[i];
    int e = (u >> 7) & 0xFF;
    bool insane = (e >= 133) || (e > 0 && e <= 96) || (e == 0 && (u & 0x7F) != 0);
    cnt += insane ? 1 : 0;
  }
#pragma unroll
  for (int off = 32; off >= 1; off >>= 1) cnt += __shfl_xor(cnt, off);
  if (lane == 0) *flag = (cnt > 400) ? 1 : 0;   // 1 = inputs are fp32
}

// ---------------- kernel 0b: convert x to bf16 -------------------------------
__global__ __launch_bounds__(256) void convert_x(const void* __restrict__ xr,
                                                 const int* __restrict__ flag,
                                                 bf16* __restrict__ xb, int n)
{
  int i = (blockIdx.x * blockDim.x + threadIdx.x) * 4;
  if (i >= n) return;
  if (*flag) {
    float4 v = *(const float4*)((const float*)xr + i);
    __align__(8) bf16 o[4] = {(bf16)v.x, (bf16)v.y, (bf16)v.z, (bf16)v.w};
    *(uint2*)(xb + i) = *(uint2*)o;
  } else {
    *(uint2*)(xb + i) = *(const uint2*)((const bf16*)xr + i);
  }
}

// ---------------- kernel 0c: biases -> fp32, mask -> float shift -------------
__global__ __launch_bounds__(1024) void prep_aux(
    const void* b0, const void* b1, const void* b2, const void* b3,
    const int* __restrict__ mask,
    const int* __restrict__ flag, float* __restrict__ bf, float* __restrict__ mf)
{
  const void* ps[4] = {b0, b1, b2, b3};
  int fl = *flag;
  for (int t = threadIdx.x; t < 4 * D_MODEL; t += 1024) {
    int w = t >> 9, o = t & 511;
    bf[t] = fl ? ((const float*)ps[w])[o] : (float)((const bf16*)ps[w])[o];
  }
  for (int j = threadIdx.x; j < M_ROWS; j += 1024)
    mf[j] = mask[j] ? -16.0f : -1e30f;     // fixed-shift (exp2 domain) + mask
}

// ---------------- kernel 1: per-output-channel weight quant-dequant ----------
__global__ __launch_bounds__(256) void qdq_weights(
    const void* __restrict__ Wq, const void* __restrict__ Wk,
    const void* __restrict__ Wv, const void* __restrict__ Wo,
    const int* __restrict__ flag, bf16* __restrict__ out)
{
  int wave = threadIdx.x >> 6, lane = threadIdx.x & 63;
  int gid = blockIdx.x * 4 + wave;
  int w = gid >> 9, row = gid & 511;
  const void* W = (w == 0) ? Wq : (w == 1) ? Wk : (w == 2) ? Wv : Wo;
  int fl = *flag;
  float v[8]; float amax = 0.f;
#pragma unroll
  for (int i = 0; i < 8; i++) {
    int idx = row * D_MODEL + lane + 64 * i;
    v[i] = fl ? ((const float*)W)[idx] : (float)((const bf16*)W)[idx];
    amax = fmaxf(amax, fabsf(v[i]));
  }
#pragma unroll
  for (int off = 32; off >= 1; off >>= 1) amax = fmaxf(amax, __shfl_xor(amax, off));
  float s = fmaxf(amax / 127.0f, 1e-8f);
  bf16* dst = out + (size_t)gid * D_MODEL;
#pragma unroll
  for (int i = 0; i < 8; i++) {
    float q = rintf(v[i] / s);
    q = fminf(fmaxf(q, -127.f), 127.f);
    dst[lane + 64*i] = (bf16)(q * s);
  }
}

// ---------------- kernel 2a: fused QKV GEMM ----------------------------------
// Q/K written HEAD-MAJOR: Qh/Kh[(b*8+h)][t 0..4095][64] (contiguous per head)
// V written to VTP[ch 0..511][VROW tokens] (row stride 16448 B, non-pow2)
#define LDS_STRIDE 40
__global__ __launch_bounds__(256) void gemm_qkv(
    const bf16* __restrict__ A, const bf16* __restrict__ W,
    const float* __restrict__ bias,
    bf16* __restrict__ Qh, bf16* __restrict__ Kh, bf16* __restrict__ VTP)
{
  __shared__ __align__(16) bf16 As[128 * LDS_STRIDE];
  __shared__ __align__(16) bf16 Bs[128 * LDS_STRIDE];

  const int tid = threadIdx.x;
  const int wave = tid >> 6, lane = tid & 63;
  const int lr = lane & 15, quad = lane >> 4;
  const int wm = (wave >> 1) * 64, wn = (wave & 1) * 64;
  const int m0 = blockIdx.x * 128, n0 = blockIdx.y * 128;
  const int sec = blockIdx.y >> 2;   // 0=Q 1=K 2=V

  f32x4 acc[4][4];
#pragma unroll
  for (int i = 0; i < 4; i++)
#pragma unroll
    for (int j = 0; j < 4; j++) acc[i][j] = f32x4{0.f, 0.f, 0.f, 0.f};

  const int srow = tid >> 2;
  const int sseg = (tid & 3) * 8;

  for (int k0 = 0; k0 < D_MODEL; k0 += 32) {
#pragma unroll
    for (int i = 0; i < 2; i++) {
      int r = srow + i * 64;
      *(uint4*)&As[r * LDS_STRIDE + sseg] = *(const uint4*)(A + (size_t)(m0 + r) * D_MODEL + k0 + sseg);
      *(uint4*)&Bs[r * LDS_STRIDE + sseg] = *(const uint4*)(W + (size_t)(n0 + r) * D_MODEL + k0 + sseg);
    }
    __syncthreads();
    bf16x8 af[4], bfr[4];
#pragma unroll
    for (int mt = 0; mt < 4; mt++) af[mt]  = *(bf16x8*)&As[(wm + mt*16 + lr) * LDS_STRIDE + quad*8];
#pragma unroll
    for (int nt = 0; nt < 4; nt++) bfr[nt] = *(bf16x8*)&Bs[(wn + nt*16 + lr) * LDS_STRIDE + quad*8];
#pragma unroll
    for (int mt = 0; mt < 4; mt++)
#pragma unroll
      for (int nt = 0; nt < 4; nt++)
        acc[mt][nt] = __builtin_amdgcn_mfma_f32_16x16x32_bf16(af[mt], bfr[nt], acc[mt][nt], 0, 0, 0);
    __syncthreads();
  }

  const float scale = (sec == 0) ? QK_SCALE : 1.0f;
#pragma unroll
  for (int mt = 0; mt < 4; mt++) {
    int grow = m0 + wm + mt * 16 + quad * 4;
#pragma unroll
    for (int nt = 0; nt < 4; nt++) {
      int gcol = n0 + wn + nt * 16 + lr;
      float b = bias[gcol];
      if (sec == 2) {               // VTP[ch][token], packed x4, padded row
        bf16x4v pk;
#pragma unroll
        for (int r = 0; r < 4; r++) pk[r] = (bf16)(acc[mt][nt][r] + b);
        *(bf16x4v*)(VTP + (size_t)(gcol - 1024) * VROW + grow) = pk;
      } else {                      // head-major planes
        bf16* dst = (sec == 0) ? Qh : Kh;
        int c = gcol & 511;
        int hh = c >> 6, c64 = c & 63;
#pragma unroll
        for (int r = 0; r < 4; r++) {
          int row = grow + r;
          int bb = row >> 12, t = row & 4095;
          dst[((size_t)(bb * NH + hh) * T_SEQ + t) * DH + c64] =
              (bf16)((acc[mt][nt][r] + b) * scale);
        }
      }
    }
  }
}

// ---------------- kernel 2b: O-proj GEMM, 64x128, fp32 out + absmax ----------
__global__ __launch_bounds__(256) void gemm_o(
    const bf16* __restrict__ A, const bf16* __restrict__ W,
    const float* __restrict__ bias,
    float* __restrict__ Cf, unsigned int* __restrict__ amaxp)
{
  __shared__ __align__(16) bf16 As[64 * LDS_STRIDE];
  __shared__ __align__(16) bf16 Bs[128 * LDS_STRIDE];
  __shared__ float wred[4];

  const int tid = threadIdx.x;
  const int wave = tid >> 6, lane = tid & 63;
  const int lr = lane & 15, quad = lane >> 4;
  const int wm = (wave >> 1) * 32, wn = (wave & 1) * 64;
  const int m0 = blockIdx.x * 64, n0 = blockIdx.y * 128;

  f32x4 acc[2][4];
#pragma unroll
  for (int i = 0; i < 2; i++)
#pragma unroll
    for (int j = 0; j < 4; j++) acc[i][j] = f32x4{0.f, 0.f, 0.f, 0.f};

  const int srow = tid >> 2;
  const int sseg = (tid & 3) * 8;

  for (int k0 = 0; k0 < D_MODEL; k0 += 32) {
    *(uint4*)&As[srow * LDS_STRIDE + sseg] = *(const uint4*)(A + (size_t)(m0 + srow) * D_MODEL + k0 + sseg);
#pragma unroll
    for (int i = 0; i < 2; i++) {
      int r = srow + i * 64;
      *(uint4*)&Bs[r * LDS_STRIDE + sseg] = *(const uint4*)(W + (size_t)(n0 + r) * D_MODEL + k0 + sseg);
    }
    __syncthreads();
    bf16x8 af[2], bfr[4];
#pragma unroll
    for (int mt = 0; mt < 2; mt++) af[mt]  = *(bf16x8*)&As[(wm + mt*16 + lr) * LDS_STRIDE + quad*8];
#pragma unroll
    for (int nt = 0; nt < 4; nt++) bfr[nt] = *(bf16x8*)&Bs[(wn + nt*16 + lr) * LDS_STRIDE + quad*8];
#pragma unroll
    for (int mt = 0; mt < 2; mt++)
#pragma unroll
      for (int nt = 0; nt < 4; nt++)
        acc[mt][nt] = __builtin_amdgcn_mfma_f32_16x16x32_bf16(af[mt], bfr[nt], acc[mt][nt], 0, 0, 0);
    __syncthreads();
  }

  float lmax = 0.f;
#pragma unroll
  for (int mt = 0; mt < 2; mt++) {
    int grow = m0 + wm + mt * 16 + quad * 4;
#pragma unroll
    for (int nt = 0; nt < 4; nt++) {
      int gcol = n0 + wn + nt * 16 + lr;
      float b = bias[gcol];
#pragma unroll
      for (int r = 0; r < 4; r++) {
        float v = acc[mt][nt][r] + b;
        Cf[(size_t)(grow + r) * D_MODEL + gcol] = v;
        lmax = fmaxf(lmax, fabsf(v));
      }
    }
  }
#pragma unroll
  for (int off = 32; off >= 1; off >>= 1) lmax = fmaxf(lmax, __shfl_xor(lmax, off));
  if (lane == 0) wred[wave] = lmax;
  __syncthreads();
  if (tid == 0) {
    float m = fmaxf(fmaxf(wred[0], wred[1]), fmaxf(wred[2], wred[3]));
    atomicMax(amaxp, __float_as_uint(m));
  }
}

// ---------------- kernel 3: split-K flash attention, PHASE-ROTATED -----------
// 1024 blocks x 128 thr (2 waves). Block owns 64 q-rows of one (b,h);
// wave w processes keys [2048w, 2048w+2048). Fixed exp2 shift (-16) =>
// order-invariant accumulation => each block starts its key loop at chunk
// (qb % 32) and wraps. R0-R4 evidence: chunk-period flat ~5000-6200 cy
// across 1/2/4 waves/SIMD => shared-queue bottleneck; all ~64 blocks of a
// (b,h) streamed the SAME K/V bytes in phase (convoy on the same L2 lines).
// Rotation spreads concurrent readers over 32 distinct 16KB regions.
#define PB_STRIDE 72
__global__ __launch_bounds__(128, 1) void attn(
    const bf16* __restrict__ Q, const bf16* __restrict__ K, const bf16* __restrict__ VT,
    const float* __restrict__ maskf, bf16* __restrict__ ctx)
{
  __shared__ __align__(16) bf16 Pb[2][64 * PB_STRIDE];   // 18432 B

  const int lane = threadIdx.x & 63;
  const int wave = threadIdx.x >> 6;        // key-half selector
  const int lr = lane & 15, quad = lane >> 4;
  // XCD swizzle: linear%8 = XCD -> give each XCD 2 bh values
  const int i = blockIdx.x;
  const int bh = (i & 7) * 2 + ((i >> 3) & 1);
  const int qb = i >> 4;                    // 0..63
  const int b = bh >> 3, h = bh & 7;
  const int q0 = qb * 64;

  const int kb0 = wave * 2048;
  bf16* Pw = Pb[wave];

  const bf16* Qb = Q  + (size_t)bh * T_SEQ * DH;       // Qh[bh][t][64]
  const bf16* Kb = K  + (size_t)bh * T_SEQ * DH;       // Kh[bh][t][64]
  const bf16* Vb = VT + (size_t)(h * DH) * VROW + b * T_SEQ;  // VTP[ch][VROW]
  const float* mb = maskf + b * T_SEQ;

  // Q as B-frags: qf[qt][kh], B[k=dh][n=q=lr]
  bf16x8 qf[4][2];
#pragma unroll
  for (int qt = 0; qt < 4; qt++) {
    const bf16* rq = Qb + (size_t)(q0 + qt*16 + lr) * DH;
    qf[qt][0] = *(const bf16x8*)(rq + quad * 8);
    qf[qt][1] = *(const bf16x8*)(rq + 32 + quad * 8);
  }

  f32x4 O[4][4];   // O[qt][nt]: C-layout row=quad*4+r (q), col=lr (dh)
#pragma unroll
  for (int a = 0; a < 4; a++)
#pragma unroll
    for (int c = 0; c < 4; c++) O[a][c] = f32x4{0.f, 0.f, 0.f, 0.f};
  float lacc[4] = {0.f, 0.f, 0.f, 0.f};

  // A-frag K: kr[kt][kh] = K[kb+kt*16+lr][dh = kh*32+quad*8 ..+8]
  // B-frag V: vr[nt][ks] = V[key = ks*32+quad*8 ..+8][dh = nt*16+lr]
  bf16x8 kr[4][2], vr[4][2];
  f32x4 mk[4];

  const int phase = qb & 31;                // de-phasing rotation
  int cc = phase;                           // current chunk index 0..31
  {
    const int kb = kb0 + cc * 64;
#pragma unroll
    for (int kt = 0; kt < 4; kt++) {
      const bf16* rk = Kb + (size_t)(kb + kt*16 + lr) * DH;
      kr[kt][0] = *(const bf16x8*)(rk + quad*8);
      kr[kt][1] = *(const bf16x8*)(rk + 32 + quad*8);
      mk[kt] = *(const f32x4*)(mb + kb + kt*16 + quad*4);
    }
#pragma unroll
    for (int nt = 0; nt < 4; nt++) {
      const bf16* rv = Vb + (size_t)(nt*16 + lr) * VROW + kb;
      vr[nt][0] = *(const bf16x8*)(rv + quad*8);
      vr[nt][1] = *(const bf16x8*)(rv + 32 + quad*8);
    }
  }

  for (int j = 0; j < 32; j++) {
    const bool nxt = (j + 1) < 32;
    const int ccn = (cc + 1) & 31;
    const int kbn = kb0 + ccn * 64;         // next chunk base (wrapped)

    // S^T = K.Q^T per (qt,kt); mask+shift as C-init; exp2 -> Pw
#pragma unroll
    for (int qt = 0; qt < 4; qt++) {
      f32x4 z[4];
#pragma unroll
      for (int kt = 0; kt < 4; kt++) {
        f32x4 t = mk[kt];
        t = __builtin_amdgcn_mfma_f32_16x16x32_bf16(kr[kt][0], qf[qt][0], t, 0, 0, 0);
        t = __builtin_amdgcn_mfma_f32_16x16x32_bf16(kr[kt][1], qf[qt][1], t, 0, 0, 0);
        z[kt] = t;
      }
      float la = lacc[qt];
#pragma unroll
      for (int kt = 0; kt < 4; kt++) {
        bf16x4v pk;
#pragma unroll
        for (int r = 0; r < 4; r++) {
          float p = __builtin_amdgcn_exp2f(z[kt][r]);
          la += p;
          pk[r] = (bf16)p;
        }
        *(bf16x4v*)&Pw[(qt*16 + lr) * PB_STRIDE + kt*16 + quad*4] = pk;
      }
      lacc[qt] = la;
    }

    if (nxt) {  // kr & mk dead -> prefetch next chunk's K + mask
#pragma unroll
      for (int kt = 0; kt < 4; kt++) {
        const bf16* rk = Kb + (size_t)(kbn + kt*16 + lr) * DH;
        kr[kt][0] = *(const bf16x8*)(rk + quad*8);
        kr[kt][1] = *(const bf16x8*)(rk + 32 + quad*8);
        mk[kt] = *(const f32x4*)(mb + kbn + kt*16 + quad*4);
      }
    }

    // P back as A-frags (same-wave LDS, ordered)
    bf16x8 pf[4][2];
#pragma unroll
    for (int qt = 0; qt < 4; qt++) {
      pf[qt][0] = *(bf16x8*)&Pw[(qt*16 + lr) * PB_STRIDE + quad*8];
      pf[qt][1] = *(bf16x8*)&Pw[(qt*16 + lr) * PB_STRIDE + 32 + quad*8];
    }

    // PV accumulate
#pragma unroll
    for (int nt = 0; nt < 4; nt++)
#pragma unroll
      for (int qt = 0; qt < 4; qt++) {
        O[qt][nt] = __builtin_amdgcn_mfma_f32_16x16x32_bf16(pf[qt][0], vr[nt][0], O[qt][nt], 0, 0, 0);
        O[qt][nt] = __builtin_amdgcn_mfma_f32_16x16x32_bf16(pf[qt][1], vr[nt][1], O[qt][nt], 0, 0, 0);
      }

    if (nxt) {  // vr dead -> prefetch next chunk's V
#pragma unroll
      for (int nt = 0; nt < 4; nt++) {
        const bf16* rv = Vb + (size_t)(nt*16 + lr) * VROW + kbn;
        vr[nt][0] = *(const bf16x8*)(rv + quad*8);
        vr[nt][1] = *(const bf16x8*)(rv + 32 + quad*8);
      }
    }
    cc = ccn;
  }

  // ---- cross-wave combine: O += O_other, l += l_other (fixed shift => add) --
  __syncthreads();                       // both waves done with their Pb
  float* Osh = (float*)&Pb[0][0];        // 16384 B (overlays dead Pb)
  float* Lsh = Osh + 4096;               // 1024 B
  if (wave == 1) {
#pragma unroll
    for (int qt = 0; qt < 4; qt++) {
#pragma unroll
      for (int nt = 0; nt < 4; nt++)
        *(f32x4*)&Osh[((qt*4 + nt) * 64 + lane) * 4] = O[qt][nt];
      Lsh[qt * 64 + lane] = lacc[qt];
    }
  }
  __syncthreads();
  if (wave == 0) {
#pragma unroll
    for (int qt = 0; qt < 4; qt++) {
#pragma unroll
      for (int nt = 0; nt < 4; nt++) {
        f32x4 o2 = *(const f32x4*)&Osh[((qt*4 + nt) * 64 + lane) * 4];
        O[qt][nt] += o2;
      }
      lacc[qt] += Lsh[qt * 64 + lane];
    }

    // epilogue: normalize + store
#pragma unroll
    for (int qt = 0; qt < 4; qt++) {
      float ls = lacc[qt];
      ls += __shfl_xor(ls, 16);
      ls += __shfl_xor(ls, 32);
      float linv = 1.0f / ls;
      float lO[4];
#pragma unroll
      for (int r = 0; r < 4; r++) lO[r] = __shfl(linv, quad*4 + r);
#pragma unroll
      for (int nt = 0; nt < 4; nt++)
#pragma unroll
        for (int r = 0; r < 4; r++) {
          size_t row = (size_t)(b * T_SEQ + q0 + qt*16 + quad*4 + r);
          ctx[row * D_MODEL + h * DH + nt*16 + lr] = (bf16)(O[qt][nt][r] * lO[r]);
        }
    }
  }
}

// ---------------- kernel 4: per-tensor activation quant-dequant --------------
__global__ __launch_bounds__(256) void act_qdq(
    const float* __restrict__ pre, const unsigned int* __restrict__ amaxp,
    const int* __restrict__ flag, void* __restrict__ outv, int n)
{
  int i = (blockIdx.x * blockDim.x + threadIdx.x) * 4;
  if (i >= n) return;
  float s = fmaxf(__uint_as_float(*amaxp) / 127.0f, 1e-8f);
  float4 v = *(const float4*)(pre + i);
  float o[4] = {v.x, v.y, v.z, v.w};
#pragma unroll
  for (int r = 0; r < 4; r++) {
    float q = rintf(o[r] / s);
    q = fminf(fmaxf(q, -127.f), 127.f);
    o[r] = q * s;
  }
  if (*flag) {
    *(float4*)((float*)outv + i) = make_float4(o[0], o[1], o[2], o[3]);
  } else {
    __align__(8) bf16 ob[4] = {(bf16)o[0], (bf16)o[1], (bf16)o[2], (bf16)o[3]};
    *(uint2*)((bf16*)outv + i) = *(uint2*)ob;
  }
}

// ---------------- launch -----------------------------------------------------
extern "C" void kernel_launch(void* const* d_in, const int* in_sizes, int n_in,
                              void* d_out, int out_size, void* d_ws, size_t ws_size,
                              hipStream_t stream) {
  const void* x    = d_in[0];
  const int*  mask = (const int*)d_in[1];
  const void* Wq = d_in[2]; const void* bq = d_in[3];
  const void* Wk = d_in[4]; const void* bk = d_in[5];
  const void* Wv = d_in[6]; const void* bv = d_in[7];
  const void* Wo = d_in[8]; const void* bo = d_in[9];

  char* ws = (char*)d_ws;
  int*  flag  = (int*)(ws + 0);
  unsigned int* amax = (unsigned int*)(ws + 64);
  float* biasf = (float*)(ws + 1024);                 // 8 KB
  float* maskf = (float*)(ws + 16384);                // 32 KB
  bf16* Wt  = (bf16*)(ws + 65536);                    // 2 MB
  bf16* xb  = (bf16*)(ws + 4194304);                  // 8 MB
  bf16* Qm  = (bf16*)(ws + 12582912);                 // 8 MB head-major planes
  bf16* Km  = (bf16*)(ws + 20971520);                 // 8 MB head-major planes
  bf16* VT  = (bf16*)(ws + 29360128);                 // 8.42 MB: VTP[ch][8224]
  bf16* Cm  = (bf16*)(ws + 4194304);                  // overlays xb
  float* pre = (float*)(ws + 12582912);               // overlays Qm+Km

  hipMemsetAsync(amax, 0, 4, stream);
  detect_dtype<<<1, 64, 0, stream>>>((const unsigned short*)x, flag);
  convert_x<<<4096, 256, 0, stream>>>(x, flag, xb, M_ROWS * D_MODEL);
  prep_aux<<<1, 1024, 0, stream>>>(bq, bk, bv, bo, mask, flag, biasf, maskf);
  qdq_weights<<<512, 256, 0, stream>>>(Wq, Wk, Wv, Wo, flag, Wt);
  gemm_qkv<<<dim3(64, 12), 256, 0, stream>>>(xb, Wt, biasf, Qm, Km, VT);
  attn<<<1024, 128, 0, stream>>>(Qm, Km, VT, maskf, Cm);
  gemm_o<<<dim3(128, 4), 256, 0, stream>>>(Cm, Wt + 3*262144, biasf + 1536, pre, amax);
  act_qdq<<<4096, 256, 0, stream>>>(pre, amax, flag, d_out, M_ROWS * D_MODEL);
}

// Round 6
// 242.543 us; speedup vs baseline: 1.6356x; 1.0794x over previous
//
#include <hip/hip_runtime.h>
#include <hip/hip_bf16.h>

typedef __bf16 bf16;
typedef __bf16 bf16x8 __attribute__((ext_vector_type(8)));
typedef __bf16 bf16x4v __attribute__((ext_vector_type(4)));
typedef float f32x4 __attribute__((ext_vector_type(4)));

#define D_MODEL 512
#define T_SEQ   4096
#define NH      8
#define DH      64
#define M_ROWS  8192   // B*T
#define VROW    8224   // 8192 + 32 pad tokens: V row stride 16448 B (non-pow2)
#define QK_SCALE 0.18033688011112042f   // 0.125 * log2(e), folded into Q

// async global->LDS, 16B per lane, linear LDS dest (wave base + lane*16)
__device__ __forceinline__ void gload16(const void* g, void* l) {
  __builtin_amdgcn_global_load_lds(
      (const __attribute__((address_space(1))) unsigned int*)g,
      (__attribute__((address_space(3))) unsigned int*)l, 16, 0, 0);
}

// ---------------- kernel 0: dtype detector ----------------------------------
__global__ __launch_bounds__(64) void detect_dtype(const unsigned short* __restrict__ xr,
                                                   int* __restrict__ flag)
{
  int lane = threadIdx.x;
  int cnt = 0;
  for (int i = lane; i < 4096; i += 64) {
    unsigned short u = xr[i];
    int e = (u >> 7) & 0xFF;
    bool insane = (e >= 133) || (e > 0 && e <= 96) || (e == 0 && (u & 0x7F) != 0);
    cnt += insane ? 1 : 0;
  }
#pragma unroll
  for (int off = 32; off >= 1; off >>= 1) cnt += __shfl_xor(cnt, off);
  if (lane == 0) *flag = (cnt > 400) ? 1 : 0;   // 1 = inputs are fp32
}

// ---------------- kernel 0b: convert x to bf16 -------------------------------
__global__ __launch_bounds__(256) void convert_x(const void* __restrict__ xr,
                                                 const int* __restrict__ flag,
                                                 bf16* __restrict__ xb, int n)
{
  int i = (blockIdx.x * blockDim.x + threadIdx.x) * 4;
  if (i >= n) return;
  if (*flag) {
    float4 v = *(const float4*)((const float*)xr + i);
    __align__(8) bf16 o[4] = {(bf16)v.x, (bf16)v.y, (bf16)v.z, (bf16)v.w};
    *(uint2*)(xb + i) = *(uint2*)o;
  } else {
    *(uint2*)(xb + i) = *(const uint2*)((const bf16*)xr + i);
  }
}

// ---------------- kernel 0c: biases -> fp32, mask -> float shift -------------
__global__ __launch_bounds__(1024) void prep_aux(
    const void* b0, const void* b1, const void* b2, const void* b3,
    const int* __restrict__ mask,
    const int* __restrict__ flag, float* __restrict__ bf, float* __restrict__ mf)
{
  const void* ps[4] = {b0, b1, b2, b3};
  int fl = *flag;
  for (int t = threadIdx.x; t < 4 * D_MODEL; t += 1024) {
    int w = t >> 9, o = t & 511;
    bf[t] = fl ? ((const float*)ps[w])[o] : (float)((const bf16*)ps[w])[o];
  }
  for (int j = threadIdx.x; j < M_ROWS; j += 1024)
    mf[j] = mask[j] ? -16.0f : -1e30f;     // fixed-shift (exp2 domain) + mask
}

// ---------------- kernel 1: per-output-channel weight quant-dequant ----------
__global__ __launch_bounds__(256) void qdq_weights(
    const void* __restrict__ Wq, const void* __restrict__ Wk,
    const void* __restrict__ Wv, const void* __restrict__ Wo,
    const int* __restrict__ flag, bf16* __restrict__ out)
{
  int wave = threadIdx.x >> 6, lane = threadIdx.x & 63;
  int gid = blockIdx.x * 4 + wave;
  int w = gid >> 9, row = gid & 511;
  const void* W = (w == 0) ? Wq : (w == 1) ? Wk : (w == 2) ? Wv : Wo;
  int fl = *flag;
  float v[8]; float amax = 0.f;
#pragma unroll
  for (int i = 0; i < 8; i++) {
    int idx = row * D_MODEL + lane + 64 * i;
    v[i] = fl ? ((const float*)W)[idx] : (float)((const bf16*)W)[idx];
    amax = fmaxf(amax, fabsf(v[i]));
  }
#pragma unroll
  for (int off = 32; off >= 1; off >>= 1) amax = fmaxf(amax, __shfl_xor(amax, off));
  float s = fmaxf(amax / 127.0f, 1e-8f);
  bf16* dst = out + (size_t)gid * D_MODEL;
#pragma unroll
  for (int i = 0; i < 8; i++) {
    float q = rintf(v[i] / s);
    q = fminf(fmaxf(q, -127.f), 127.f);
    dst[lane + 64*i] = (bf16)(q * s);
  }
}

// ---------------- kernel 2a: fused QKV GEMM ----------------------------------
// Q/K written HEAD-MAJOR: Qh/Kh[(b*8+h)][t 0..4095][64] (contiguous per head)
// V written to VTP[ch 0..511][VROW tokens] (row stride 16448 B, non-pow2)
#define LDS_STRIDE 40
__global__ __launch_bounds__(256) void gemm_qkv(
    const bf16* __restrict__ A, const bf16* __restrict__ W,
    const float* __restrict__ bias,
    bf16* __restrict__ Qh, bf16* __restrict__ Kh, bf16* __restrict__ VTP)
{
  __shared__ __align__(16) bf16 As[128 * LDS_STRIDE];
  __shared__ __align__(16) bf16 Bs[128 * LDS_STRIDE];

  const int tid = threadIdx.x;
  const int wave = tid >> 6, lane = tid & 63;
  const int lr = lane & 15, quad = lane >> 4;
  const int wm = (wave >> 1) * 64, wn = (wave & 1) * 64;
  const int m0 = blockIdx.x * 128, n0 = blockIdx.y * 128;
  const int sec = blockIdx.y >> 2;   // 0=Q 1=K 2=V

  f32x4 acc[4][4];
#pragma unroll
  for (int i = 0; i < 4; i++)
#pragma unroll
    for (int j = 0; j < 4; j++) acc[i][j] = f32x4{0.f, 0.f, 0.f, 0.f};

  const int srow = tid >> 2;
  const int sseg = (tid & 3) * 8;

  for (int k0 = 0; k0 < D_MODEL; k0 += 32) {
#pragma unroll
    for (int i = 0; i < 2; i++) {
      int r = srow + i * 64;
      *(uint4*)&As[r * LDS_STRIDE + sseg] = *(const uint4*)(A + (size_t)(m0 + r) * D_MODEL + k0 + sseg);
      *(uint4*)&Bs[r * LDS_STRIDE + sseg] = *(const uint4*)(W + (size_t)(n0 + r) * D_MODEL + k0 + sseg);
    }
    __syncthreads();
    bf16x8 af[4], bfr[4];
#pragma unroll
    for (int mt = 0; mt < 4; mt++) af[mt]  = *(bf16x8*)&As[(wm + mt*16 + lr) * LDS_STRIDE + quad*8];
#pragma unroll
    for (int nt = 0; nt < 4; nt++) bfr[nt] = *(bf16x8*)&Bs[(wn + nt*16 + lr) * LDS_STRIDE + quad*8];
#pragma unroll
    for (int mt = 0; mt < 4; mt++)
#pragma unroll
      for (int nt = 0; nt < 4; nt++)
        acc[mt][nt] = __builtin_amdgcn_mfma_f32_16x16x32_bf16(af[mt], bfr[nt], acc[mt][nt], 0, 0, 0);
    __syncthreads();
  }

  const float scale = (sec == 0) ? QK_SCALE : 1.0f;
#pragma unroll
  for (int mt = 0; mt < 4; mt++) {
    int grow = m0 + wm + mt * 16 + quad * 4;
#pragma unroll
    for (int nt = 0; nt < 4; nt++) {
      int gcol = n0 + wn + nt * 16 + lr;
      float b = bias[gcol];
      if (sec == 2) {               // VTP[ch][token], packed x4, padded row
        bf16x4v pk;
#pragma unroll
        for (int r = 0; r < 4; r++) pk[r] = (bf16)(acc[mt][nt][r] + b);
        *(bf16x4v*)(VTP + (size_t)(gcol - 1024) * VROW + grow) = pk;
      } else {                      // head-major planes
        bf16* dst = (sec == 0) ? Qh : Kh;
        int c = gcol & 511;
        int hh = c >> 6, c64 = c & 63;
#pragma unroll
        for (int r = 0; r < 4; r++) {
          int row = grow + r;
          int bb = row >> 12, t = row & 4095;
          dst[((size_t)(bb * NH + hh) * T_SEQ + t) * DH + c64] =
              (bf16)((acc[mt][nt][r] + b) * scale);
        }
      }
    }
  }
}

// ---------------- kernel 2b: O-proj GEMM, 64x128, fp32 out + absmax ----------
__global__ __launch_bounds__(256) void gemm_o(
    const bf16* __restrict__ A, const bf16* __restrict__ W,
    const float* __restrict__ bias,
    float* __restrict__ Cf, unsigned int* __restrict__ amaxp)
{
  __shared__ __align__(16) bf16 As[64 * LDS_STRIDE];
  __shared__ __align__(16) bf16 Bs[128 * LDS_STRIDE];
  __shared__ float wred[4];

  const int tid = threadIdx.x;
  const int wave = tid >> 6, lane = tid & 63;
  const int lr = lane & 15, quad = lane >> 4;
  const int wm = (wave >> 1) * 32, wn = (wave & 1) * 64;
  const int m0 = blockIdx.x * 64, n0 = blockIdx.y * 128;

  f32x4 acc[2][4];
#pragma unroll
  for (int i = 0; i < 2; i++)
#pragma unroll
    for (int j = 0; j < 4; j++) acc[i][j] = f32x4{0.f, 0.f, 0.f, 0.f};

  const int srow = tid >> 2;
  const int sseg = (tid & 3) * 8;

  for (int k0 = 0; k0 < D_MODEL; k0 += 32) {
    *(uint4*)&As[srow * LDS_STRIDE + sseg] = *(const uint4*)(A + (size_t)(m0 + srow) * D_MODEL + k0 + sseg);
#pragma unroll
    for (int i = 0; i < 2; i++) {
      int r = srow + i * 64;
      *(uint4*)&Bs[r * LDS_STRIDE + sseg] = *(const uint4*)(W + (size_t)(n0 + r) * D_MODEL + k0 + sseg);
    }
    __syncthreads();
    bf16x8 af[2], bfr[4];
#pragma unroll
    for (int mt = 0; mt < 2; mt++) af[mt]  = *(bf16x8*)&As[(wm + mt*16 + lr) * LDS_STRIDE + quad*8];
#pragma unroll
    for (int nt = 0; nt < 4; nt++) bfr[nt] = *(bf16x8*)&Bs[(wn + nt*16 + lr) * LDS_STRIDE + quad*8];
#pragma unroll
    for (int mt = 0; mt < 2; mt++)
#pragma unroll
      for (int nt = 0; nt < 4; nt++)
        acc[mt][nt] = __builtin_amdgcn_mfma_f32_16x16x32_bf16(af[mt], bfr[nt], acc[mt][nt], 0, 0, 0);
    __syncthreads();
  }

  float lmax = 0.f;
#pragma unroll
  for (int mt = 0; mt < 2; mt++) {
    int grow = m0 + wm + mt * 16 + quad * 4;
#pragma unroll
    for (int nt = 0; nt < 4; nt++) {
      int gcol = n0 + wn + nt * 16 + lr;
      float b = bias[gcol];
#pragma unroll
      for (int r = 0; r < 4; r++) {
        float v = acc[mt][nt][r] + b;
        Cf[(size_t)(grow + r) * D_MODEL + gcol] = v;
        lmax = fmaxf(lmax, fabsf(v));
      }
    }
  }
#pragma unroll
  for (int off = 32; off >= 1; off >>= 1) lmax = fmaxf(lmax, __shfl_xor(lmax, off));
  if (lane == 0) wred[wave] = lmax;
  __syncthreads();
  if (tid == 0) {
    float m = fmaxf(fmaxf(wred[0], wred[1]), fmaxf(wred[2], wred[3]));
    atomicMax(amaxp, __float_as_uint(m));
  }
}

// ---------------- kernel 3: LDS-staged shared-KV flash attention -------------
// 512 blocks x 256 thr (4 waves). Block owns (b,h) x 128 q-rows; waves split
// q (32 rows each) and SHARE the staged key stream -> aggregate global K/V
// traffic HALVES to 0.54 GB (R0-R5 evidence: attn time == global-bytes /
// ~8-9 TB/s in every config -> only byte reduction moves the needle).
// Per chunk: K(8KB)+V(8KB) double-buffered via global_load_lds (linear dest,
// XOR-pre-swizzled SOURCE + swizzled ds_read: both-sides rule), one barrier.
// Mask row (16KB f32) staged once -> in-loop vmcnt domain = stage DMAs only.
// No split-K => no cross-wave combine. Phase rotation kept (+12% in R5).
#define PB_STRIDE 72
__global__ __launch_bounds__(256, 2) void attn(
    const bf16* __restrict__ Q, const bf16* __restrict__ K, const bf16* __restrict__ VT,
    const float* __restrict__ maskf, bf16* __restrict__ ctx)
{
  __shared__ __align__(16) bf16 Ks[2][64 * 64];          // 16 KB
  __shared__ __align__(16) bf16 Vs[2][64 * 64];          // 16 KB
  __shared__ __align__(16) float Mf[T_SEQ];              // 16 KB
  __shared__ __align__(16) bf16 Pb[4][32 * PB_STRIDE];   // 18 KB

  const int tid = threadIdx.x;
  const int wave = tid >> 6, lane = tid & 63;
  const int lr = lane & 15, quad = lane >> 4;
  // XCD swizzle: linear%8 = XCD -> 2 bh per XCD, all q-blocks of a bh on one XCD
  const int i = blockIdx.x;
  const int bh = (i & 7) * 2 + ((i >> 3) & 1);
  const int qb = i >> 4;                    // 0..31
  const int b = bh >> 3, h = bh & 7;
  const int q0 = qb * 128 + wave * 32;

  const bf16* Qb = Q + (size_t)bh * T_SEQ * DH;                 // Qh[bh][t][64]
  const bf16* Kb = K + (size_t)bh * T_SEQ * DH;                 // Kh[bh][t][64]
  const bf16* Vb = VT + (size_t)(h * DH) * VROW + (size_t)b * T_SEQ; // VTP rows
  const float* mb = maskf + b * T_SEQ;
  bf16* Pw = Pb[wave];

  const int phase = (qb * 2) & 63;          // de-phase blocks of same bh
  int cc = phase;

  // ---- prologue: stage full mask row + first K/V chunk; load Q frags ----
#pragma unroll
  for (int ii = 0; ii < 4; ii++) {
    int g = ii * 256 + tid;
    gload16(mb + g * 4, &Mf[g * 4]);
  }
  {
    int kb = cc * 64;
#pragma unroll
    for (int ii = 0; ii < 2; ii++) {
      int s = ii * 256 + tid, row = s >> 3, sl = s & 7;
      gload16(Kb + (size_t)(kb + row) * DH + ((sl ^ (row & 7)) << 3), &Ks[0][s * 8]);
      gload16(Vb + (size_t)row * VROW + kb + ((sl ^ (row & 7)) << 3), &Vs[0][s * 8]);
    }
  }

  bf16x8 qf[2][2];       // Q as B-frags: B[k=dh][n=q=lr]
#pragma unroll
  for (int qt = 0; qt < 2; qt++) {
    const bf16* rq = Qb + (size_t)(q0 + qt * 16 + lr) * DH;
    qf[qt][0] = *(const bf16x8*)(rq + quad * 8);
    qf[qt][1] = *(const bf16x8*)(rq + 32 + quad * 8);
  }

  f32x4 O[2][4];         // O[qt][nt]: C-layout row=quad*4+r (q), col=lr (dh)
#pragma unroll
  for (int a = 0; a < 2; a++)
#pragma unroll
    for (int c = 0; c < 4; c++) O[a][c] = f32x4{0.f, 0.f, 0.f, 0.f};
  float lacc[2] = {0.f, 0.f};

  __syncthreads();       // drains prologue DMA + Q loads

  int cur = 0;
  for (int j = 0; j < 64; j++) {
    const bool nxt = (j + 1) < 64;
    const int ccn = (cc + 1) & 63;

    if (nxt) {           // async-stage next chunk into the other buffer
      int kb = ccn * 64;
#pragma unroll
      for (int ii = 0; ii < 2; ii++) {
        int s = ii * 256 + tid, row = s >> 3, sl = s & 7;
        gload16(Kb + (size_t)(kb + row) * DH + ((sl ^ (row & 7)) << 3), &Ks[cur ^ 1][s * 8]);
        gload16(Vb + (size_t)row * VROW + kb + ((sl ^ (row & 7)) << 3), &Vs[cur ^ 1][s * 8]);
      }
    }

    // mask C-init from LDS (broadcast reads)
    f32x4 mk[4];
#pragma unroll
    for (int kt = 0; kt < 4; kt++)
      mk[kt] = *(const f32x4*)&Mf[cc * 64 + kt * 16 + quad * 4];

    // K A-frags from swizzled LDS: row=kt*16+lr, logical 16B-slot kh*4+quad
    bf16x8 kr[4][2];
#pragma unroll
    for (int kt = 0; kt < 4; kt++)
#pragma unroll
      for (int kh = 0; kh < 2; kh++)
        kr[kt][kh] = *(const bf16x8*)&Ks[cur][(kt * 16 + lr) * 64 +
                                             (((kh * 4 + quad) ^ (lr & 7)) << 3)];

    // S^T = K.Q^T; mask+shift as C-init; exp2 -> Pw
#pragma unroll
    for (int qt = 0; qt < 2; qt++) {
      f32x4 z[4];
#pragma unroll
      for (int kt = 0; kt < 4; kt++) {
        f32x4 t = mk[kt];
        t = __builtin_amdgcn_mfma_f32_16x16x32_bf16(kr[kt][0], qf[qt][0], t, 0, 0, 0);
        t = __builtin_amdgcn_mfma_f32_16x16x32_bf16(kr[kt][1], qf[qt][1], t, 0, 0, 0);
        z[kt] = t;
      }
      float la = lacc[qt];
#pragma unroll
      for (int kt = 0; kt < 4; kt++) {
        bf16x4v pk;
#pragma unroll
        for (int r = 0; r < 4; r++) {
          float p = __builtin_amdgcn_exp2f(z[kt][r]);
          la += p;
          pk[r] = (bf16)p;
        }
        *(bf16x4v*)&Pw[(qt * 16 + lr) * PB_STRIDE + kt * 16 + quad * 4] = pk;
      }
      lacc[qt] = la;
    }

    // P back as A-frags (same-wave LDS, ordered)
    bf16x8 pf[2][2];
#pragma unroll
    for (int qt = 0; qt < 2; qt++) {
      pf[qt][0] = *(bf16x8*)&Pw[(qt * 16 + lr) * PB_STRIDE + quad * 8];
      pf[qt][1] = *(bf16x8*)&Pw[(qt * 16 + lr) * PB_STRIDE + 32 + quad * 8];
    }

    // V B-frags from swizzled LDS: row=nt*16+lr, logical slot ks*4+quad
    bf16x8 vr[4][2];
#pragma unroll
    for (int nt = 0; nt < 4; nt++)
#pragma unroll
      for (int ks = 0; ks < 2; ks++)
        vr[nt][ks] = *(const bf16x8*)&Vs[cur][(nt * 16 + lr) * 64 +
                                             (((ks * 4 + quad) ^ (lr & 7)) << 3)];

    // PV accumulate
#pragma unroll
    for (int nt = 0; nt < 4; nt++)
#pragma unroll
      for (int qt = 0; qt < 2; qt++) {
        O[qt][nt] = __builtin_amdgcn_mfma_f32_16x16x32_bf16(pf[qt][0], vr[nt][0], O[qt][nt], 0, 0, 0);
        O[qt][nt] = __builtin_amdgcn_mfma_f32_16x16x32_bf16(pf[qt][1], vr[nt][1], O[qt][nt], 0, 0, 0);
      }

    // one barrier per chunk: drains stage DMA (vmcnt) and guards buffer reuse
    __syncthreads();
    cur ^= 1; cc = ccn;
  }

  // epilogue: normalize + store (each wave owns its 32 q-rows; no combine)
#pragma unroll
  for (int qt = 0; qt < 2; qt++) {
    float ls = lacc[qt];
    ls += __shfl_xor(ls, 16);
    ls += __shfl_xor(ls, 32);
    float linv = 1.0f / ls;
    float lO[4];
#pragma unroll
    for (int r = 0; r < 4; r++) lO[r] = __shfl(linv, quad * 4 + r);
#pragma unroll
    for (int nt = 0; nt < 4; nt++)
#pragma unroll
      for (int r = 0; r < 4; r++) {
        size_t row = (size_t)(b * T_SEQ + q0 + qt * 16 + quad * 4 + r);
        ctx[row * D_MODEL + h * DH + nt * 16 + lr] = (bf16)(O[qt][nt][r] * lO[r]);
      }
  }
}

// ---------------- kernel 4: per-tensor activation quant-dequant --------------
__global__ __launch_bounds__(256) void act_qdq(
    const float* __restrict__ pre, const unsigned int* __restrict__ amaxp,
    const int* __restrict__ flag, void* __restrict__ outv, int n)
{
  int i = (blockIdx.x * blockDim.x + threadIdx.x) * 4;
  if (i >= n) return;
  float s = fmaxf(__uint_as_float(*amaxp) / 127.0f, 1e-8f);
  float4 v = *(const float4*)(pre + i);
  float o[4] = {v.x, v.y, v.z, v.w};
#pragma unroll
  for (int r = 0; r < 4; r++) {
    float q = rintf(o[r] / s);
    q = fminf(fmaxf(q, -127.f), 127.f);
    o[r] = q * s;
  }
  if (*flag) {
    *(float4*)((float*)outv + i) = make_float4(o[0], o[1], o[2], o[3]);
  } else {
    __align__(8) bf16 ob[4] = {(bf16)o[0], (bf16)o[1], (bf16)o[2], (bf16)o[3]};
    *(uint2*)((bf16*)outv + i) = *(uint2*)ob;
  }
}

// ---------------- launch -----------------------------------------------------
extern "C" void kernel_launch(void* const* d_in, const int* in_sizes, int n_in,
                              void* d_out, int out_size, void* d_ws, size_t ws_size,
                              hipStream_t stream) {
  const void* x    = d_in[0];
  const int*  mask = (const int*)d_in[1];
  const void* Wq = d_in[2]; const void* bq = d_in[3];
  const void* Wk = d_in[4]; const void* bk = d_in[5];
  const void* Wv = d_in[6]; const void* bv = d_in[7];
  const void* Wo = d_in[8]; const void* bo = d_in[9];

  char* ws = (char*)d_ws;
  int*  flag  = (int*)(ws + 0);
  unsigned int* amax = (unsigned int*)(ws + 64);
  float* biasf = (float*)(ws + 1024);                 // 8 KB
  float* maskf = (float*)(ws + 16384);                // 32 KB
  bf16* Wt  = (bf16*)(ws + 65536);                    // 2 MB
  bf16* xb  = (bf16*)(ws + 4194304);                  // 8 MB
  bf16* Qm  = (bf16*)(ws + 12582912);                 // 8 MB head-major planes
  bf16* Km  = (bf16*)(ws + 20971520);                 // 8 MB head-major planes
  bf16* VT  = (bf16*)(ws + 29360128);                 // 8.42 MB: VTP[ch][8224]
  bf16* Cm  = (bf16*)(ws + 4194304);                  // overlays xb
  float* pre = (float*)(ws + 12582912);               // overlays Qm+Km

  hipMemsetAsync(amax, 0, 4, stream);
  detect_dtype<<<1, 64, 0, stream>>>((const unsigned short*)x, flag);
  convert_x<<<4096, 256, 0, stream>>>(x, flag, xb, M_ROWS * D_MODEL);
  prep_aux<<<1, 1024, 0, stream>>>(bq, bk, bv, bo, mask, flag, biasf, maskf);
  qdq_weights<<<512, 256, 0, stream>>>(Wq, Wk, Wv, Wo, flag, Wt);
  gemm_qkv<<<dim3(64, 12), 256, 0, stream>>>(xb, Wt, biasf, Qm, Km, VT);
  attn<<<512, 256, 0, stream>>>(Qm, Km, VT, maskf, Cm);
  gemm_o<<<dim3(128, 4), 256, 0, stream>>>(Cm, Wt + 3*262144, biasf + 1536, pre, amax);
  act_qdq<<<4096, 256, 0, stream>>>(pre, amax, flag, d_out, M_ROWS * D_MODEL);
}

// Round 7
// 223.793 us; speedup vs baseline: 1.7726x; 1.0838x over previous
//
#include <hip/hip_runtime.h>
#include <hip/hip_bf16.h>

typedef __bf16 bf16;
typedef __bf16 bf16x8 __attribute__((ext_vector_type(8)));
typedef __bf16 bf16x4v __attribute__((ext_vector_type(4)));
typedef float f32x4 __attribute__((ext_vector_type(4)));

#define D_MODEL 512
#define T_SEQ   4096
#define NH      8
#define DH      64
#define M_ROWS  8192   // B*T
#define VROW    8224   // 8192 + 32 pad tokens: V row stride 16448 B (non-pow2)
#define QK_SCALE 0.18033688011112042f   // 0.125 * log2(e), folded into Q

// async global->LDS, 16B per lane, linear LDS dest (wave base + lane*16)
__device__ __forceinline__ void gload16(const void* g, void* l) {
  __builtin_amdgcn_global_load_lds(
      (const __attribute__((address_space(1))) unsigned int*)g,
      (__attribute__((address_space(3))) unsigned int*)l, 16, 0, 0);
}

// ---------------- kernel 0: dtype detector ----------------------------------
__global__ __launch_bounds__(64) void detect_dtype(const unsigned short* __restrict__ xr,
                                                   int* __restrict__ flag)
{
  int lane = threadIdx.x;
  int cnt = 0;
  for (int i = lane; i < 4096; i += 64) {
    unsigned short u = xr[i];
    int e = (u >> 7) & 0xFF;
    bool insane = (e >= 133) || (e > 0 && e <= 96) || (e == 0 && (u & 0x7F) != 0);
    cnt += insane ? 1 : 0;
  }
#pragma unroll
  for (int off = 32; off >= 1; off >>= 1) cnt += __shfl_xor(cnt, off);
  if (lane == 0) *flag = (cnt > 400) ? 1 : 0;   // 1 = inputs are fp32
}

// ---------------- kernel 0b: convert x to bf16 -------------------------------
__global__ __launch_bounds__(256) void convert_x(const void* __restrict__ xr,
                                                 const int* __restrict__ flag,
                                                 bf16* __restrict__ xb, int n)
{
  int i = (blockIdx.x * blockDim.x + threadIdx.x) * 4;
  if (i >= n) return;
  if (*flag) {
    float4 v = *(const float4*)((const float*)xr + i);
    __align__(8) bf16 o[4] = {(bf16)v.x, (bf16)v.y, (bf16)v.z, (bf16)v.w};
    *(uint2*)(xb + i) = *(uint2*)o;
  } else {
    *(uint2*)(xb + i) = *(const uint2*)((const bf16*)xr + i);
  }
}

// ---------------- kernel 0c: biases -> fp32, mask -> float shift -------------
__global__ __launch_bounds__(1024) void prep_aux(
    const void* b0, const void* b1, const void* b2, const void* b3,
    const int* __restrict__ mask,
    const int* __restrict__ flag, float* __restrict__ bf, float* __restrict__ mf)
{
  const void* ps[4] = {b0, b1, b2, b3};
  int fl = *flag;
  for (int t = threadIdx.x; t < 4 * D_MODEL; t += 1024) {
    int w = t >> 9, o = t & 511;
    bf[t] = fl ? ((const float*)ps[w])[o] : (float)((const bf16*)ps[w])[o];
  }
  for (int j = threadIdx.x; j < M_ROWS; j += 1024)
    mf[j] = mask[j] ? -16.0f : -1e30f;     // fixed-shift (exp2 domain) + mask
}

// ---------------- kernel 1: per-output-channel weight quant-dequant ----------
__global__ __launch_bounds__(256) void qdq_weights(
    const void* __restrict__ Wq, const void* __restrict__ Wk,
    const void* __restrict__ Wv, const void* __restrict__ Wo,
    const int* __restrict__ flag, bf16* __restrict__ out)
{
  int wave = threadIdx.x >> 6, lane = threadIdx.x & 63;
  int gid = blockIdx.x * 4 + wave;
  int w = gid >> 9, row = gid & 511;
  const void* W = (w == 0) ? Wq : (w == 1) ? Wk : (w == 2) ? Wv : Wo;
  int fl = *flag;
  float v[8]; float amax = 0.f;
#pragma unroll
  for (int i = 0; i < 8; i++) {
    int idx = row * D_MODEL + lane + 64 * i;
    v[i] = fl ? ((const float*)W)[idx] : (float)((const bf16*)W)[idx];
    amax = fmaxf(amax, fabsf(v[i]));
  }
#pragma unroll
  for (int off = 32; off >= 1; off >>= 1) amax = fmaxf(amax, __shfl_xor(amax, off));
  float s = fmaxf(amax / 127.0f, 1e-8f);
  bf16* dst = out + (size_t)gid * D_MODEL;
#pragma unroll
  for (int i = 0; i < 8; i++) {
    float q = rintf(v[i] / s);
    q = fminf(fmaxf(q, -127.f), 127.f);
    dst[lane + 64*i] = (bf16)(q * s);
  }
}

// ---------------- kernel 2a: fused QKV GEMM ----------------------------------
// Q/K written HEAD-MAJOR: Qh/Kh[(b*8+h)][t 0..4095][64] (contiguous per head)
// V written to VTP[ch 0..511][VROW tokens] (row stride 16448 B, non-pow2)
#define LDS_STRIDE 40
__global__ __launch_bounds__(256) void gemm_qkv(
    const bf16* __restrict__ A, const bf16* __restrict__ W,
    const float* __restrict__ bias,
    bf16* __restrict__ Qh, bf16* __restrict__ Kh, bf16* __restrict__ VTP)
{
  __shared__ __align__(16) bf16 As[128 * LDS_STRIDE];
  __shared__ __align__(16) bf16 Bs[128 * LDS_STRIDE];

  const int tid = threadIdx.x;
  const int wave = tid >> 6, lane = tid & 63;
  const int lr = lane & 15, quad = lane >> 4;
  const int wm = (wave >> 1) * 64, wn = (wave & 1) * 64;
  const int m0 = blockIdx.x * 128, n0 = blockIdx.y * 128;
  const int sec = blockIdx.y >> 2;   // 0=Q 1=K 2=V

  f32x4 acc[4][4];
#pragma unroll
  for (int i = 0; i < 4; i++)
#pragma unroll
    for (int j = 0; j < 4; j++) acc[i][j] = f32x4{0.f, 0.f, 0.f, 0.f};

  const int srow = tid >> 2;
  const int sseg = (tid & 3) * 8;

  for (int k0 = 0; k0 < D_MODEL; k0 += 32) {
#pragma unroll
    for (int i = 0; i < 2; i++) {
      int r = srow + i * 64;
      *(uint4*)&As[r * LDS_STRIDE + sseg] = *(const uint4*)(A + (size_t)(m0 + r) * D_MODEL + k0 + sseg);
      *(uint4*)&Bs[r * LDS_STRIDE + sseg] = *(const uint4*)(W + (size_t)(n0 + r) * D_MODEL + k0 + sseg);
    }
    __syncthreads();
    bf16x8 af[4], bfr[4];
#pragma unroll
    for (int mt = 0; mt < 4; mt++) af[mt]  = *(bf16x8*)&As[(wm + mt*16 + lr) * LDS_STRIDE + quad*8];
#pragma unroll
    for (int nt = 0; nt < 4; nt++) bfr[nt] = *(bf16x8*)&Bs[(wn + nt*16 + lr) * LDS_STRIDE + quad*8];
#pragma unroll
    for (int mt = 0; mt < 4; mt++)
#pragma unroll
      for (int nt = 0; nt < 4; nt++)
        acc[mt][nt] = __builtin_amdgcn_mfma_f32_16x16x32_bf16(af[mt], bfr[nt], acc[mt][nt], 0, 0, 0);
    __syncthreads();
  }

  const float scale = (sec == 0) ? QK_SCALE : 1.0f;
#pragma unroll
  for (int mt = 0; mt < 4; mt++) {
    int grow = m0 + wm + mt * 16 + quad * 4;
#pragma unroll
    for (int nt = 0; nt < 4; nt++) {
      int gcol = n0 + wn + nt * 16 + lr;
      float b = bias[gcol];
      if (sec == 2) {               // VTP[ch][token], packed x4, padded row
        bf16x4v pk;
#pragma unroll
        for (int r = 0; r < 4; r++) pk[r] = (bf16)(acc[mt][nt][r] + b);
        *(bf16x4v*)(VTP + (size_t)(gcol - 1024) * VROW + grow) = pk;
      } else {                      // head-major planes
        bf16* dst = (sec == 0) ? Qh : Kh;
        int c = gcol & 511;
        int hh = c >> 6, c64 = c & 63;
#pragma unroll
        for (int r = 0; r < 4; r++) {
          int row = grow + r;
          int bb = row >> 12, t = row & 4095;
          dst[((size_t)(bb * NH + hh) * T_SEQ + t) * DH + c64] =
              (bf16)((acc[mt][nt][r] + b) * scale);
        }
      }
    }
  }
}

// ---------------- kernel 2b: O-proj GEMM, 64x128, fp32 out + absmax ----------
__global__ __launch_bounds__(256) void gemm_o(
    const bf16* __restrict__ A, const bf16* __restrict__ W,
    const float* __restrict__ bias,
    float* __restrict__ Cf, unsigned int* __restrict__ amaxp)
{
  __shared__ __align__(16) bf16 As[64 * LDS_STRIDE];
  __shared__ __align__(16) bf16 Bs[128 * LDS_STRIDE];
  __shared__ float wred[4];

  const int tid = threadIdx.x;
  const int wave = tid >> 6, lane = tid & 63;
  const int lr = lane & 15, quad = lane >> 4;
  const int wm = (wave >> 1) * 32, wn = (wave & 1) * 64;
  const int m0 = blockIdx.x * 64, n0 = blockIdx.y * 128;

  f32x4 acc[2][4];
#pragma unroll
  for (int i = 0; i < 2; i++)
#pragma unroll
    for (int j = 0; j < 4; j++) acc[i][j] = f32x4{0.f, 0.f, 0.f, 0.f};

  const int srow = tid >> 2;
  const int sseg = (tid & 3) * 8;

  for (int k0 = 0; k0 < D_MODEL; k0 += 32) {
    *(uint4*)&As[srow * LDS_STRIDE + sseg] = *(const uint4*)(A + (size_t)(m0 + srow) * D_MODEL + k0 + sseg);
#pragma unroll
    for (int i = 0; i < 2; i++) {
      int r = srow + i * 64;
      *(uint4*)&Bs[r * LDS_STRIDE + sseg] = *(const uint4*)(W + (size_t)(n0 + r) * D_MODEL + k0 + sseg);
    }
    __syncthreads();
    bf16x8 af[2], bfr[4];
#pragma unroll
    for (int mt = 0; mt < 2; mt++) af[mt]  = *(bf16x8*)&As[(wm + mt*16 + lr) * LDS_STRIDE + quad*8];
#pragma unroll
    for (int nt = 0; nt < 4; nt++) bfr[nt] = *(bf16x8*)&Bs[(wn + nt*16 + lr) * LDS_STRIDE + quad*8];
#pragma unroll
    for (int mt = 0; mt < 2; mt++)
#pragma unroll
      for (int nt = 0; nt < 4; nt++)
        acc[mt][nt] = __builtin_amdgcn_mfma_f32_16x16x32_bf16(af[mt], bfr[nt], acc[mt][nt], 0, 0, 0);
    __syncthreads();
  }

  float lmax = 0.f;
#pragma unroll
  for (int mt = 0; mt < 2; mt++) {
    int grow = m0 + wm + mt * 16 + quad * 4;
#pragma unroll
    for (int nt = 0; nt < 4; nt++) {
      int gcol = n0 + wn + nt * 16 + lr;
      float b = bias[gcol];
#pragma unroll
      for (int r = 0; r < 4; r++) {
        float v = acc[mt][nt][r] + b;
        Cf[(size_t)(grow + r) * D_MODEL + gcol] = v;
        lmax = fmaxf(lmax, fabsf(v));
      }
    }
  }
#pragma unroll
  for (int off = 32; off >= 1; off >>= 1) lmax = fmaxf(lmax, __shfl_xor(lmax, off));
  if (lane == 0) wred[wave] = lmax;
  __syncthreads();
  if (tid == 0) {
    float m = fmaxf(fmaxf(wred[0], wred[1]), fmaxf(wred[2], wred[3]));
    atomicMax(amaxp, __float_as_uint(m));
  }
}

// ---------------- kernel 3: LDS-staged flash attention, in-register P --------
// 512 blocks x 256 thr (4 waves). Block owns (b,h) x 128 q-rows; waves split
// q (32 rows each) and share the staged key stream (R6: halved global traffic).
// R7 change: K rows staged PERMUTED -- LDS row (kt,m) holds global key
//   keymap = (m>>2)*8 + (kt&1)*4 + (m&3) + (kt>>1)*32
// so QK^T's C-layout output per lane IS the PV A-frag in natural key order:
//   pf[ks] = pack(exp2(z[2ks][0..3]), exp2(z[2ks+1][0..3]))   (lane-local!)
// The P LDS roundtrip (8 ds_write + 4 ds_read + lgkm chain + 18KB Pb) is gone.
// Mask C-init reads use the same permutation (still contiguous f32x4).
// V/Q/epilogue unchanged; key-sum order-invariance keeps lacc/reduce correct.
__global__ __launch_bounds__(256, 2) void attn(
    const bf16* __restrict__ Q, const bf16* __restrict__ K, const bf16* __restrict__ VT,
    const float* __restrict__ maskf, bf16* __restrict__ ctx)
{
  __shared__ __align__(16) bf16 Ks[2][64 * 64];          // 16 KB
  __shared__ __align__(16) bf16 Vs[2][64 * 64];          // 16 KB
  __shared__ __align__(16) float Mf[T_SEQ];              // 16 KB

  const int tid = threadIdx.x;
  const int wave = tid >> 6, lane = tid & 63;
  const int lr = lane & 15, quad = lane >> 4;
  // XCD swizzle: linear%8 = XCD -> 2 bh per XCD, all q-blocks of a bh on one XCD
  const int i = blockIdx.x;
  const int bh = (i & 7) * 2 + ((i >> 3) & 1);
  const int qb = i >> 4;                    // 0..31
  const int b = bh >> 3, h = bh & 7;
  const int q0 = qb * 128 + wave * 32;

  const bf16* Qb = Q + (size_t)bh * T_SEQ * DH;                 // Qh[bh][t][64]
  const bf16* Kb = K + (size_t)bh * T_SEQ * DH;                 // Kh[bh][t][64]
  const bf16* Vb = VT + (size_t)(h * DH) * VROW + (size_t)b * T_SEQ; // VTP rows
  const float* mb = maskf + b * T_SEQ;

  const int phase = (qb * 2) & 63;          // de-phase blocks of same bh
  int cc = phase;

  // per-thread staging bases (constant across chunks)
  // slot s = ii*256+tid; LDS row = s>>3, 16B-slot sl = s&7 (XOR pre-swizzle)
  const bf16* kSrc[2]; const bf16* vSrc[2];
#pragma unroll
  for (int ii = 0; ii < 2; ii++) {
    int s = ii * 256 + tid, row = s >> 3, sl = s & 7;
    int kt = row >> 4, m = row & 15;
    int keym = ((m >> 2) << 3) + ((kt & 1) << 2) + (m & 3) + ((kt >> 1) << 5);
    kSrc[ii] = Kb + (size_t)keym * DH + ((sl ^ (row & 7)) << 3);
    vSrc[ii] = Vb + (size_t)row * VROW + ((sl ^ (row & 7)) << 3);
  }

  // ---- prologue: stage full mask row + first K/V chunk; load Q frags ----
#pragma unroll
  for (int ii = 0; ii < 4; ii++) {
    int g = ii * 256 + tid;
    gload16(mb + g * 4, &Mf[g * 4]);
  }
  {
    int kb = cc * 64;
#pragma unroll
    for (int ii = 0; ii < 2; ii++) {
      int s = ii * 256 + tid;
      gload16(kSrc[ii] + (size_t)kb * DH, &Ks[0][s * 8]);
      gload16(vSrc[ii] + kb, &Vs[0][s * 8]);
    }
  }

  bf16x8 qf[2][2];       // Q as B-frags: B[k=dh][n=q=lr]
#pragma unroll
  for (int qt = 0; qt < 2; qt++) {
    const bf16* rq = Qb + (size_t)(q0 + qt * 16 + lr) * DH;
    qf[qt][0] = *(const bf16x8*)(rq + quad * 8);
    qf[qt][1] = *(const bf16x8*)(rq + 32 + quad * 8);
  }

  f32x4 O[2][4];         // O[qt][nt]: C-layout row=quad*4+r (q), col=lr (dh)
#pragma unroll
  for (int a = 0; a < 2; a++)
#pragma unroll
    for (int c = 0; c < 4; c++) O[a][c] = f32x4{0.f, 0.f, 0.f, 0.f};
  float lacc[2] = {0.f, 0.f};

  __syncthreads();       // drains prologue DMA + Q loads

  int cur = 0;
  for (int j = 0; j < 64; j++) {
    const bool nxt = (j + 1) < 64;
    const int ccn = (cc + 1) & 63;

    if (nxt) {           // async-stage next chunk into the other buffer
      int kb = ccn * 64;
#pragma unroll
      for (int ii = 0; ii < 2; ii++) {
        int s = ii * 256 + tid;
        gload16(kSrc[ii] + (size_t)kb * DH, &Ks[cur ^ 1][s * 8]);
        gload16(vSrc[ii] + kb, &Vs[cur ^ 1][s * 8]);
      }
    }

    // mask C-init from LDS, PERMUTED to match K-row staging:
    // mk[kt][r] = maskshift[key (kt>>1)*32 + quad*8 + (kt&1)*4 + r]
    f32x4 mk[4];
#pragma unroll
    for (int kt = 0; kt < 4; kt++)
      mk[kt] = *(const f32x4*)&Mf[cc * 64 + ((kt >> 1) << 5) + (quad << 3) + ((kt & 1) << 2)];

    // K A-frags from swizzled LDS: row=kt*16+lr, logical 16B-slot kh*4+quad
    bf16x8 kr[4][2];
#pragma unroll
    for (int kt = 0; kt < 4; kt++)
#pragma unroll
      for (int kh = 0; kh < 2; kh++)
        kr[kt][kh] = *(const bf16x8*)&Ks[cur][(kt * 16 + lr) * 64 +
                                             (((kh * 4 + quad) ^ (lr & 7)) << 3)];

    // S^T = K.Q^T (permuted keys); exp2 -> in-register PV A-frags
    bf16x8 pfa[2][2];
#pragma unroll
    for (int qt = 0; qt < 2; qt++) {
      f32x4 z[4];
#pragma unroll
      for (int kt = 0; kt < 4; kt++) {
        f32x4 t = mk[kt];
        t = __builtin_amdgcn_mfma_f32_16x16x32_bf16(kr[kt][0], qf[qt][0], t, 0, 0, 0);
        t = __builtin_amdgcn_mfma_f32_16x16x32_bf16(kr[kt][1], qf[qt][1], t, 0, 0, 0);
        z[kt] = t;
      }
      float la = lacc[qt];
#pragma unroll
      for (int kt = 0; kt < 4; kt++) {
#pragma unroll
        for (int r = 0; r < 4; r++) {
          float p = __builtin_amdgcn_exp2f(z[kt][r]);
          la += p;
          pfa[qt][kt >> 1][((kt & 1) << 2) + r] = (bf16)p;
        }
      }
      lacc[qt] = la;
    }

    // V B-frags from swizzled LDS: row=nt*16+lr, logical slot ks*4+quad
    bf16x8 vr[4][2];
#pragma unroll
    for (int nt = 0; nt < 4; nt++)
#pragma unroll
      for (int ks = 0; ks < 2; ks++)
        vr[nt][ks] = *(const bf16x8*)&Vs[cur][(nt * 16 + lr) * 64 +
                                             (((ks * 4 + quad) ^ (lr & 7)) << 3)];

    // PV accumulate (pfa is natural-key-order A-frag)
#pragma unroll
    for (int nt = 0; nt < 4; nt++)
#pragma unroll
      for (int qt = 0; qt < 2; qt++) {
        O[qt][nt] = __builtin_amdgcn_mfma_f32_16x16x32_bf16(pfa[qt][0], vr[nt][0], O[qt][nt], 0, 0, 0);
        O[qt][nt] = __builtin_amdgcn_mfma_f32_16x16x32_bf16(pfa[qt][1], vr[nt][1], O[qt][nt], 0, 0, 0);
      }

    // one barrier per chunk: drains stage DMA (vmcnt) and guards buffer reuse
    __syncthreads();
    cur ^= 1; cc = ccn;
  }

  // epilogue: normalize + store (each wave owns its 32 q-rows; no combine)
#pragma unroll
  for (int qt = 0; qt < 2; qt++) {
    float ls = lacc[qt];
    ls += __shfl_xor(ls, 16);
    ls += __shfl_xor(ls, 32);
    float linv = 1.0f / ls;
    float lO[4];
#pragma unroll
    for (int r = 0; r < 4; r++) lO[r] = __shfl(linv, quad * 4 + r);
#pragma unroll
    for (int nt = 0; nt < 4; nt++)
#pragma unroll
      for (int r = 0; r < 4; r++) {
        size_t row = (size_t)(b * T_SEQ + q0 + qt * 16 + quad * 4 + r);
        ctx[row * D_MODEL + h * DH + nt * 16 + lr] = (bf16)(O[qt][nt][r] * lO[r]);
      }
  }
}

// ---------------- kernel 4: per-tensor activation quant-dequant --------------
__global__ __launch_bounds__(256) void act_qdq(
    const float* __restrict__ pre, const unsigned int* __restrict__ amaxp,
    const int* __restrict__ flag, void* __restrict__ outv, int n)
{
  int i = (blockIdx.x * blockDim.x + threadIdx.x) * 4;
  if (i >= n) return;
  float s = fmaxf(__uint_as_float(*amaxp) / 127.0f, 1e-8f);
  float4 v = *(const float4*)(pre + i);
  float o[4] = {v.x, v.y, v.z, v.w};
#pragma unroll
  for (int r = 0; r < 4; r++) {
    float q = rintf(o[r] / s);
    q = fminf(fmaxf(q, -127.f), 127.f);
    o[r] = q * s;
  }
  if (*flag) {
    *(float4*)((float*)outv + i) = make_float4(o[0], o[1], o[2], o[3]);
  } else {
    __align__(8) bf16 ob[4] = {(bf16)o[0], (bf16)o[1], (bf16)o[2], (bf16)o[3]};
    *(uint2*)((bf16*)outv + i) = *(uint2*)ob;
  }
}

// ---------------- launch -----------------------------------------------------
extern "C" void kernel_launch(void* const* d_in, const int* in_sizes, int n_in,
                              void* d_out, int out_size, void* d_ws, size_t ws_size,
                              hipStream_t stream) {
  const void* x    = d_in[0];
  const int*  mask = (const int*)d_in[1];
  const void* Wq = d_in[2]; const void* bq = d_in[3];
  const void* Wk = d_in[4]; const void* bk = d_in[5];
  const void* Wv = d_in[6]; const void* bv = d_in[7];
  const void* Wo = d_in[8]; const void* bo = d_in[9];

  char* ws = (char*)d_ws;
  int*  flag  = (int*)(ws + 0);
  unsigned int* amax = (unsigned int*)(ws + 64);
  float* biasf = (float*)(ws + 1024);                 // 8 KB
  float* maskf = (float*)(ws + 16384);                // 32 KB
  bf16* Wt  = (bf16*)(ws + 65536);                    // 2 MB
  bf16* xb  = (bf16*)(ws + 4194304);                  // 8 MB
  bf16* Qm  = (bf16*)(ws + 12582912);                 // 8 MB head-major planes
  bf16* Km  = (bf16*)(ws + 20971520);                 // 8 MB head-major planes
  bf16* VT  = (bf16*)(ws + 29360128);                 // 8.42 MB: VTP[ch][8224]
  bf16* Cm  = (bf16*)(ws + 4194304);                  // overlays xb
  float* pre = (float*)(ws + 12582912);               // overlays Qm+Km

  hipMemsetAsync(amax, 0, 4, stream);
  detect_dtype<<<1, 64, 0, stream>>>((const unsigned short*)x, flag);
  convert_x<<<4096, 256, 0, stream>>>(x, flag, xb, M_ROWS * D_MODEL);
  prep_aux<<<1, 1024, 0, stream>>>(bq, bk, bv, bo, mask, flag, biasf, maskf);
  qdq_weights<<<512, 256, 0, stream>>>(Wq, Wk, Wv, Wo, flag, Wt);
  gemm_qkv<<<dim3(64, 12), 256, 0, stream>>>(xb, Wt, biasf, Qm, Km, VT);
  attn<<<512, 256, 0, stream>>>(Qm, Km, VT, maskf, Cm);
  gemm_o<<<dim3(128, 4), 256, 0, stream>>>(Cm, Wt + 3*262144, biasf + 1536, pre, amax);
  act_qdq<<<4096, 256, 0, stream>>>(pre, amax, flag, d_out, M_ROWS * D_MODEL);
}

// Round 8
// 216.687 us; speedup vs baseline: 1.8307x; 1.0328x over previous
//
#include <hip/hip_runtime.h>
#include <hip/hip_bf16.h>

typedef __bf16 bf16;
typedef __bf16 bf16x8 __attribute__((ext_vector_type(8)));
typedef __bf16 bf16x4v __attribute__((ext_vector_type(4)));
typedef float f32x4 __attribute__((ext_vector_type(4)));

#define D_MODEL 512
#define T_SEQ   4096
#define NH      8
#define DH      64
#define M_ROWS  8192   // B*T
#define VROW    8224   // 8192 + 32 pad tokens: V row stride 16448 B (non-pow2)
#define QK_SCALE 0.18033688011112042f   // 0.125 * log2(e), folded into Q

// async global->LDS, 16B per lane, linear LDS dest (wave base + lane*16)
__device__ __forceinline__ void gload16(const void* g, void* l) {
  __builtin_amdgcn_global_load_lds(
      (const __attribute__((address_space(1))) unsigned int*)g,
      (__attribute__((address_space(3))) unsigned int*)l, 16, 0, 0);
}

#define WAITV(N) asm volatile("s_waitcnt vmcnt(" #N ")" ::: "memory")
#define CFENCE   asm volatile("" ::: "memory")

// ---------------- kernel 0: dtype detector ----------------------------------
__global__ __launch_bounds__(64) void detect_dtype(const unsigned short* __restrict__ xr,
                                                   int* __restrict__ flag)
{
  int lane = threadIdx.x;
  int cnt = 0;
  for (int i = lane; i < 4096; i += 64) {
    unsigned short u = xr[i];
    int e = (u >> 7) & 0xFF;
    bool insane = (e >= 133) || (e > 0 && e <= 96) || (e == 0 && (u & 0x7F) != 0);
    cnt += insane ? 1 : 0;
  }
#pragma unroll
  for (int off = 32; off >= 1; off >>= 1) cnt += __shfl_xor(cnt, off);
  if (lane == 0) *flag = (cnt > 400) ? 1 : 0;   // 1 = inputs are fp32
}

// ---------------- kernel 0b: convert x to bf16 -------------------------------
__global__ __launch_bounds__(256) void convert_x(const void* __restrict__ xr,
                                                 const int* __restrict__ flag,
                                                 bf16* __restrict__ xb, int n)
{
  int i = (blockIdx.x * blockDim.x + threadIdx.x) * 4;
  if (i >= n) return;
  if (*flag) {
    float4 v = *(const float4*)((const float*)xr + i);
    __align__(8) bf16 o[4] = {(bf16)v.x, (bf16)v.y, (bf16)v.z, (bf16)v.w};
    *(uint2*)(xb + i) = *(uint2*)o;
  } else {
    *(uint2*)(xb + i) = *(const uint2*)((const bf16*)xr + i);
  }
}

// ---------------- kernel 0c: biases -> fp32, mask -> float shift -------------
// grid 8 x 1024 (was 1 block; single-workgroup latency was pure overhead)
__global__ __launch_bounds__(1024) void prep_aux(
    const void* b0, const void* b1, const void* b2, const void* b3,
    const int* __restrict__ mask,
    const int* __restrict__ flag, float* __restrict__ bf, float* __restrict__ mf)
{
  const void* ps[4] = {b0, b1, b2, b3};
  int fl = *flag;
  int g = blockIdx.x * 1024 + threadIdx.x;     // 0..8191
  if (g < 4 * D_MODEL) {
    int w = g >> 9, o = g & 511;
    bf[g] = fl ? ((const float*)ps[w])[o] : (float)((const bf16*)ps[w])[o];
  }
  mf[g] = mask[g] ? -16.0f : -1e30f;           // fixed-shift (exp2 domain) + mask
}

// ---------------- kernel 1: per-output-channel weight quant-dequant ----------
__global__ __launch_bounds__(256) void qdq_weights(
    const void* __restrict__ Wq, const void* __restrict__ Wk,
    const void* __restrict__ Wv, const void* __restrict__ Wo,
    const int* __restrict__ flag, bf16* __restrict__ out)
{
  int wave = threadIdx.x >> 6, lane = threadIdx.x & 63;
  int gid = blockIdx.x * 4 + wave;
  int w = gid >> 9, row = gid & 511;
  const void* W = (w == 0) ? Wq : (w == 1) ? Wk : (w == 2) ? Wv : Wo;
  int fl = *flag;
  float v[8]; float amax = 0.f;
#pragma unroll
  for (int i = 0; i < 8; i++) {
    int idx = row * D_MODEL + lane + 64 * i;
    v[i] = fl ? ((const float*)W)[idx] : (float)((const bf16*)W)[idx];
    amax = fmaxf(amax, fabsf(v[i]));
  }
#pragma unroll
  for (int off = 32; off >= 1; off >>= 1) amax = fmaxf(amax, __shfl_xor(amax, off));
  float s = fmaxf(amax / 127.0f, 1e-8f);
  bf16* dst = out + (size_t)gid * D_MODEL;
#pragma unroll
  for (int i = 0; i < 8; i++) {
    float q = rintf(v[i] / s);
    q = fminf(fmaxf(q, -127.f), 127.f);
    dst[lane + 64*i] = (bf16)(q * s);
  }
}

// ---------------- kernel 2a: fused QKV GEMM ----------------------------------
// Q/K written HEAD-MAJOR: Qh/Kh[(b*8+h)][t 0..4095][64] (contiguous per head)
// V written to VTP[ch 0..511][VROW tokens] (row stride 16448 B, non-pow2)
#define LDS_STRIDE 40
__global__ __launch_bounds__(256) void gemm_qkv(
    const bf16* __restrict__ A, const bf16* __restrict__ W,
    const float* __restrict__ bias,
    bf16* __restrict__ Qh, bf16* __restrict__ Kh, bf16* __restrict__ VTP)
{
  __shared__ __align__(16) bf16 As[128 * LDS_STRIDE];
  __shared__ __align__(16) bf16 Bs[128 * LDS_STRIDE];

  const int tid = threadIdx.x;
  const int wave = tid >> 6, lane = tid & 63;
  const int lr = lane & 15, quad = lane >> 4;
  const int wm = (wave >> 1) * 64, wn = (wave & 1) * 64;
  const int m0 = blockIdx.x * 128, n0 = blockIdx.y * 128;
  const int sec = blockIdx.y >> 2;   // 0=Q 1=K 2=V

  f32x4 acc[4][4];
#pragma unroll
  for (int i = 0; i < 4; i++)
#pragma unroll
    for (int j = 0; j < 4; j++) acc[i][j] = f32x4{0.f, 0.f, 0.f, 0.f};

  const int srow = tid >> 2;
  const int sseg = (tid & 3) * 8;

  for (int k0 = 0; k0 < D_MODEL; k0 += 32) {
#pragma unroll
    for (int i = 0; i < 2; i++) {
      int r = srow + i * 64;
      *(uint4*)&As[r * LDS_STRIDE + sseg] = *(const uint4*)(A + (size_t)(m0 + r) * D_MODEL + k0 + sseg);
      *(uint4*)&Bs[r * LDS_STRIDE + sseg] = *(const uint4*)(W + (size_t)(n0 + r) * D_MODEL + k0 + sseg);
    }
    __syncthreads();
    bf16x8 af[4], bfr[4];
#pragma unroll
    for (int mt = 0; mt < 4; mt++) af[mt]  = *(bf16x8*)&As[(wm + mt*16 + lr) * LDS_STRIDE + quad*8];
#pragma unroll
    for (int nt = 0; nt < 4; nt++) bfr[nt] = *(bf16x8*)&Bs[(wn + nt*16 + lr) * LDS_STRIDE + quad*8];
#pragma unroll
    for (int mt = 0; mt < 4; mt++)
#pragma unroll
      for (int nt = 0; nt < 4; nt++)
        acc[mt][nt] = __builtin_amdgcn_mfma_f32_16x16x32_bf16(af[mt], bfr[nt], acc[mt][nt], 0, 0, 0);
    __syncthreads();
  }

  const float scale = (sec == 0) ? QK_SCALE : 1.0f;
#pragma unroll
  for (int mt = 0; mt < 4; mt++) {
    int grow = m0 + wm + mt * 16 + quad * 4;
#pragma unroll
    for (int nt = 0; nt < 4; nt++) {
      int gcol = n0 + wn + nt * 16 + lr;
      float b = bias[gcol];
      if (sec == 2) {               // VTP[ch][token], packed x4, padded row
        bf16x4v pk;
#pragma unroll
        for (int r = 0; r < 4; r++) pk[r] = (bf16)(acc[mt][nt][r] + b);
        *(bf16x4v*)(VTP + (size_t)(gcol - 1024) * VROW + grow) = pk;
      } else {                      // head-major planes
        bf16* dst = (sec == 0) ? Qh : Kh;
        int c = gcol & 511;
        int hh = c >> 6, c64 = c & 63;
#pragma unroll
        for (int r = 0; r < 4; r++) {
          int row = grow + r;
          int bb = row >> 12, t = row & 4095;
          dst[((size_t)(bb * NH + hh) * T_SEQ + t) * DH + c64] =
              (bf16)((acc[mt][nt][r] + b) * scale);
        }
      }
    }
  }
}

// ---------------- kernel 2b: O-proj GEMM, 64x128, fp32 out + absmax ----------
__global__ __launch_bounds__(256) void gemm_o(
    const bf16* __restrict__ A, const bf16* __restrict__ W,
    const float* __restrict__ bias,
    float* __restrict__ Cf, unsigned int* __restrict__ amaxp)
{
  __shared__ __align__(16) bf16 As[64 * LDS_STRIDE];
  __shared__ __align__(16) bf16 Bs[128 * LDS_STRIDE];
  __shared__ float wred[4];

  const int tid = threadIdx.x;
  const int wave = tid >> 6, lane = tid & 63;
  const int lr = lane & 15, quad = lane >> 4;
  const int wm = (wave >> 1) * 32, wn = (wave & 1) * 64;
  const int m0 = blockIdx.x * 64, n0 = blockIdx.y * 128;

  f32x4 acc[2][4];
#pragma unroll
  for (int i = 0; i < 2; i++)
#pragma unroll
    for (int j = 0; j < 4; j++) acc[i][j] = f32x4{0.f, 0.f, 0.f, 0.f};

  const int srow = tid >> 2;
  const int sseg = (tid & 3) * 8;

  for (int k0 = 0; k0 < D_MODEL; k0 += 32) {
    *(uint4*)&As[srow * LDS_STRIDE + sseg] = *(const uint4*)(A + (size_t)(m0 + srow) * D_MODEL + k0 + sseg);
#pragma unroll
    for (int i = 0; i < 2; i++) {
      int r = srow + i * 64;
      *(uint4*)&Bs[r * LDS_STRIDE + sseg] = *(const uint4*)(W + (size_t)(n0 + r) * D_MODEL + k0 + sseg);
    }
    __syncthreads();
    bf16x8 af[2], bfr[4];
#pragma unroll
    for (int mt = 0; mt < 2; mt++) af[mt]  = *(bf16x8*)&As[(wm + mt*16 + lr) * LDS_STRIDE + quad*8];
#pragma unroll
    for (int nt = 0; nt < 4; nt++) bfr[nt] = *(bf16x8*)&Bs[(wn + nt*16 + lr) * LDS_STRIDE + quad*8];
#pragma unroll
    for (int mt = 0; mt < 2; mt++)
#pragma unroll
      for (int nt = 0; nt < 4; nt++)
        acc[mt][nt] = __builtin_amdgcn_mfma_f32_16x16x32_bf16(af[mt], bfr[nt], acc[mt][nt], 0, 0, 0);
    __syncthreads();
  }

  float lmax = 0.f;
#pragma unroll
  for (int mt = 0; mt < 2; mt++) {
    int grow = m0 + wm + mt * 16 + quad * 4;
#pragma unroll
    for (int nt = 0; nt < 4; nt++) {
      int gcol = n0 + wn + nt * 16 + lr;
      float b = bias[gcol];
#pragma unroll
      for (int r = 0; r < 4; r++) {
        float v = acc[mt][nt][r] + b;
        Cf[(size_t)(grow + r) * D_MODEL + gcol] = v;
        lmax = fmaxf(lmax, fabsf(v));
      }
    }
  }
#pragma unroll
  for (int off = 32; off >= 1; off >>= 1) lmax = fmaxf(lmax, __shfl_xor(lmax, off));
  if (lane == 0) wred[wave] = lmax;
  __syncthreads();
  if (tid == 0) {
    float m = fmaxf(fmaxf(wred[0], wred[1]), fmaxf(wred[2], wred[3]));
    atomicMax(amaxp, __float_as_uint(m));
  }
}

// ---------------- kernel 3: flash attention, counted-vmcnt 3-deep pipeline ---
// 512 blocks x 256 thr (4 waves). Block owns (b,h) x 128 q-rows; waves split
// q (32 rows each), share the staged key stream; P fully in-register (R7).
// R8 change (T3/T4): __syncthreads (which drains vmcnt(0) every chunk and
// exposed full DMA latency -- R7's 3140 cy/chunk matches m97's known drain
// ceiling) is replaced by a 3-deep circular buffer with RAW s_barrier and
// COUNTED s_waitcnt vmcnt(8): 2 chunks of global_load_lds stay in flight
// across barriers, giving the DMA ~2 chunk-periods to complete.
// Per iter: compute(j) | bar | issue stage(j+3)->buf[j%3] | vmcnt(8) | bar.
// Tail peeled: vmcnt(4) at j=61, vmcnt(0) at j=62. 4 DMA ops/thread/chunk;
// Q-loads drained in prologue so the vmcnt ledger contains only stage DMAs.
__global__ __launch_bounds__(256, 2) void attn(
    const bf16* __restrict__ Q, const bf16* __restrict__ K, const bf16* __restrict__ VT,
    const float* __restrict__ maskf, bf16* __restrict__ ctx)
{
  __shared__ __align__(16) bf16 Ks[3][64 * 64];          // 24 KB
  __shared__ __align__(16) bf16 Vs[3][64 * 64];          // 24 KB
  __shared__ __align__(16) float Mf[T_SEQ];              // 16 KB  (64 KB total)

  const int tid = threadIdx.x;
  const int wave = tid >> 6, lane = tid & 63;
  const int lr = lane & 15, quad = lane >> 4;
  // XCD swizzle: linear%8 = XCD -> 2 bh per XCD, all q-blocks of a bh on one XCD
  const int i = blockIdx.x;
  const int bh = (i & 7) * 2 + ((i >> 3) & 1);
  const int qb = i >> 4;                    // 0..31
  const int b = bh >> 3, h = bh & 7;
  const int q0 = qb * 128 + wave * 32;

  const bf16* Qb = Q + (size_t)bh * T_SEQ * DH;                 // Qh[bh][t][64]
  const bf16* Kb = K + (size_t)bh * T_SEQ * DH;                 // Kh[bh][t][64]
  const bf16* Vb = VT + (size_t)(h * DH) * VROW + (size_t)b * T_SEQ; // VTP rows
  const float* mb = maskf + b * T_SEQ;

  const int phase = (qb * 2) & 63;          // de-phase blocks of same bh

  // per-thread staging bases (constant across chunks)
  // slot s = ii*256+tid; LDS row = s>>3, 16B-slot sl = s&7 (XOR pre-swizzle)
  // K rows PERMUTED (R7): LDS row (kt,m) holds key (m>>2)*8+(kt&1)*4+(m&3)+(kt>>1)*32
  const bf16* kSrc[2]; const bf16* vSrc[2];
#pragma unroll
  for (int ii = 0; ii < 2; ii++) {
    int s = ii * 256 + tid, row = s >> 3, sl = s & 7;
    int kt = row >> 4, m = row & 15;
    int keym = ((m >> 2) << 3) + ((kt & 1) << 2) + (m & 3) + ((kt >> 1) << 5);
    kSrc[ii] = Kb + (size_t)keym * DH + ((sl ^ (row & 7)) << 3);
    vSrc[ii] = Vb + (size_t)row * VROW + ((sl ^ (row & 7)) << 3);
  }

  // ---- prologue ----
  // 1) Q frags via regular loads, then drain so vmcnt ledger = stage DMAs only
  bf16x8 qf[2][2];       // Q as B-frags: B[k=dh][n=q=lr]
#pragma unroll
  for (int qt = 0; qt < 2; qt++) {
    const bf16* rq = Qb + (size_t)(q0 + qt * 16 + lr) * DH;
    qf[qt][0] = *(const bf16x8*)(rq + quad * 8);
    qf[qt][1] = *(const bf16x8*)(rq + 32 + quad * 8);
  }
  WAITV(0);

  // 2) mask DMA (4 ops) then chunks 0,1,2 (4 ops each) -> 16 outstanding
#pragma unroll
  for (int ii = 0; ii < 4; ii++) {
    int g = ii * 256 + tid;
    gload16(mb + g * 4, &Mf[g * 4]);
  }
#pragma unroll
  for (int d = 0; d < 3; d++) {
    int kb = ((phase + d) & 63) * 64;
#pragma unroll
    for (int ii = 0; ii < 2; ii++) {
      int s = ii * 256 + tid;
      gload16(kSrc[ii] + (size_t)kb * DH, &Ks[d][s * 8]);
      gload16(vSrc[ii] + kb, &Vs[d][s * 8]);
    }
  }

  f32x4 O[2][4];         // O[qt][nt]: C-layout row=quad*4+r (q), col=lr (dh)
#pragma unroll
  for (int a = 0; a < 2; a++)
#pragma unroll
    for (int c = 0; c < 4; c++) O[a][c] = f32x4{0.f, 0.f, 0.f, 0.f};
  float lacc[2] = {0.f, 0.f};

  WAITV(8);              // retires mask + chunk0; chunks 1,2 stay in flight
  __builtin_amdgcn_s_barrier();
  CFENCE;

  int cur = 0, cc = phase;
  for (int j = 0; j < 64; j++) {
    // mask C-init from LDS, PERMUTED to match K-row staging
    f32x4 mk[4];
#pragma unroll
    for (int kt = 0; kt < 4; kt++)
      mk[kt] = *(const f32x4*)&Mf[cc * 64 + ((kt >> 1) << 5) + (quad << 3) + ((kt & 1) << 2)];

    // K A-frags from swizzled LDS
    bf16x8 kr[4][2];
#pragma unroll
    for (int kt = 0; kt < 4; kt++)
#pragma unroll
      for (int kh = 0; kh < 2; kh++)
        kr[kt][kh] = *(const bf16x8*)&Ks[cur][(kt * 16 + lr) * 64 +
                                             (((kh * 4 + quad) ^ (lr & 7)) << 3)];

    // S^T = K.Q^T (permuted keys); exp2 -> in-register PV A-frags
    bf16x8 pfa[2][2];
#pragma unroll
    for (int qt = 0; qt < 2; qt++) {
      f32x4 z[4];
#pragma unroll
      for (int kt = 0; kt < 4; kt++) {
        f32x4 t = mk[kt];
        t = __builtin_amdgcn_mfma_f32_16x16x32_bf16(kr[kt][0], qf[qt][0], t, 0, 0, 0);
        t = __builtin_amdgcn_mfma_f32_16x16x32_bf16(kr[kt][1], qf[qt][1], t, 0, 0, 0);
        z[kt] = t;
      }
      float la = lacc[qt];
#pragma unroll
      for (int kt = 0; kt < 4; kt++) {
#pragma unroll
        for (int r = 0; r < 4; r++) {
          float p = __builtin_amdgcn_exp2f(z[kt][r]);
          la += p;
          pfa[qt][kt >> 1][((kt & 1) << 2) + r] = (bf16)p;
        }
      }
      lacc[qt] = la;
    }

    // V B-frags from swizzled LDS
    bf16x8 vr[4][2];
#pragma unroll
    for (int nt = 0; nt < 4; nt++)
#pragma unroll
      for (int ks = 0; ks < 2; ks++)
        vr[nt][ks] = *(const bf16x8*)&Vs[cur][(nt * 16 + lr) * 64 +
                                             (((ks * 4 + quad) ^ (lr & 7)) << 3)];

    // PV accumulate (pfa is natural-key-order A-frag)
#pragma unroll
    for (int nt = 0; nt < 4; nt++)
#pragma unroll
      for (int qt = 0; qt < 2; qt++) {
        O[qt][nt] = __builtin_amdgcn_mfma_f32_16x16x32_bf16(pfa[qt][0], vr[nt][0], O[qt][nt], 0, 0, 0);
        O[qt][nt] = __builtin_amdgcn_mfma_f32_16x16x32_bf16(pfa[qt][1], vr[nt][1], O[qt][nt], 0, 0, 0);
      }

    if (j < 63) {
      __builtin_amdgcn_s_barrier();   // all waves done reading buf[cur]
      CFENCE;
      if (j < 61) {                   // issue chunk cc+3 into buf[cur]
        int kb = ((cc + 3) & 63) * 64;
#pragma unroll
        for (int ii = 0; ii < 2; ii++) {
          int s = ii * 256 + tid;
          gload16(kSrc[ii] + (size_t)kb * DH, &Ks[cur][s * 8]);
          gload16(vSrc[ii] + kb, &Vs[cur][s * 8]);
        }
        WAITV(8);                     // retires chunk j+1; j+2,j+3 in flight
      } else if (j == 61) {
        WAITV(4);                     // retires chunk 62; 63 in flight
      } else {
        WAITV(0);                     // retires chunk 63
      }
      __builtin_amdgcn_s_barrier();   // chunk j+1 visible to all waves
      CFENCE;
    }
    cur = (cur == 2) ? 0 : cur + 1;
    cc = (cc + 1) & 63;
  }

  // epilogue: normalize + store (each wave owns its 32 q-rows; no combine)
#pragma unroll
  for (int qt = 0; qt < 2; qt++) {
    float ls = lacc[qt];
    ls += __shfl_xor(ls, 16);
    ls += __shfl_xor(ls, 32);
    float linv = 1.0f / ls;
    float lO[4];
#pragma unroll
    for (int r = 0; r < 4; r++) lO[r] = __shfl(linv, quad * 4 + r);
#pragma unroll
    for (int nt = 0; nt < 4; nt++)
#pragma unroll
      for (int r = 0; r < 4; r++) {
        size_t row = (size_t)(b * T_SEQ + q0 + qt * 16 + quad * 4 + r);
        ctx[row * D_MODEL + h * DH + nt * 16 + lr] = (bf16)(O[qt][nt][r] * lO[r]);
      }
  }
}

// ---------------- kernel 4: per-tensor activation quant-dequant --------------
__global__ __launch_bounds__(256) void act_qdq(
    const float* __restrict__ pre, const unsigned int* __restrict__ amaxp,
    const int* __restrict__ flag, void* __restrict__ outv, int n)
{
  int i = (blockIdx.x * blockDim.x + threadIdx.x) * 4;
  if (i >= n) return;
  float s = fmaxf(__uint_as_float(*amaxp) / 127.0f, 1e-8f);
  float4 v = *(const float4*)(pre + i);
  float o[4] = {v.x, v.y, v.z, v.w};
#pragma unroll
  for (int r = 0; r < 4; r++) {
    float q = rintf(o[r] / s);
    q = fminf(fmaxf(q, -127.f), 127.f);
    o[r] = q * s;
  }
  if (*flag) {
    *(float4*)((float*)outv + i) = make_float4(o[0], o[1], o[2], o[3]);
  } else {
    __align__(8) bf16 ob[4] = {(bf16)o[0], (bf16)o[1], (bf16)o[2], (bf16)o[3]};
    *(uint2*)((bf16*)outv + i) = *(uint2*)ob;
  }
}

// ---------------- launch -----------------------------------------------------
extern "C" void kernel_launch(void* const* d_in, const int* in_sizes, int n_in,
                              void* d_out, int out_size, void* d_ws, size_t ws_size,
                              hipStream_t stream) {
  const void* x    = d_in[0];
  const int*  mask = (const int*)d_in[1];
  const void* Wq = d_in[2]; const void* bq = d_in[3];
  const void* Wk = d_in[4]; const void* bk = d_in[5];
  const void* Wv = d_in[6]; const void* bv = d_in[7];
  const void* Wo = d_in[8]; const void* bo = d_in[9];

  char* ws = (char*)d_ws;
  int*  flag  = (int*)(ws + 0);
  unsigned int* amax = (unsigned int*)(ws + 64);
  float* biasf = (float*)(ws + 1024);                 // 8 KB
  float* maskf = (float*)(ws + 16384);                // 32 KB
  bf16* Wt  = (bf16*)(ws + 65536);                    // 2 MB
  bf16* xb  = (bf16*)(ws + 4194304);                  // 8 MB
  bf16* Qm  = (bf16*)(ws + 12582912);                 // 8 MB head-major planes
  bf16* Km  = (bf16*)(ws + 20971520);                 // 8 MB head-major planes
  bf16* VT  = (bf16*)(ws + 29360128);                 // 8.42 MB: VTP[ch][8224]
  bf16* Cm  = (bf16*)(ws + 4194304);                  // overlays xb
  float* pre = (float*)(ws + 12582912);               // overlays Qm+Km

  hipMemsetAsync(amax, 0, 4, stream);
  detect_dtype<<<1, 64, 0, stream>>>((const unsigned short*)x, flag);
  convert_x<<<4096, 256, 0, stream>>>(x, flag, xb, M_ROWS * D_MODEL);
  prep_aux<<<8, 1024, 0, stream>>>(bq, bk, bv, bo, mask, flag, biasf, maskf);
  qdq_weights<<<512, 256, 0, stream>>>(Wq, Wk, Wv, Wo, flag, Wt);
  gemm_qkv<<<dim3(64, 12), 256, 0, stream>>>(xb, Wt, biasf, Qm, Km, VT);
  attn<<<512, 256, 0, stream>>>(Qm, Km, VT, maskf, Cm);
  gemm_o<<<dim3(128, 4), 256, 0, stream>>>(Cm, Wt + 3*262144, biasf + 1536, pre, amax);
  act_qdq<<<4096, 256, 0, stream>>>(pre, amax, flag, d_out, M_ROWS * D_MODEL);
}